// Round 2
// baseline (2244.512 us; speedup 1.0000x reference)
//
#include <hip/hip_runtime.h>

typedef unsigned int  u32;
typedef unsigned short u16;

#define NND 100000
#define NE  3200000
#define F0  128
#define DIM 256
#define NC  16

typedef __bf16 bf16x8 __attribute__((ext_vector_type(8)));
typedef float  f32x4  __attribute__((ext_vector_type(4)));

__device__ __forceinline__ float b2f(u16 h){ return __uint_as_float(((u32)h)<<16); }
__device__ __forceinline__ u16 f2b(float f){
    u32 u = __float_as_uint(f);
    return (u16)((u + 0x7fffu + ((u>>16)&1u)) >> 16);
}
__device__ __forceinline__ float lo16(u32 u){ return __uint_as_float(u<<16); }
__device__ __forceinline__ float hi16(u32 u){ return __uint_as_float(u & 0xffff0000u); }

// ---------------- dtype probe ----------------
// mode[0]=1 if floats are f32 (else bf16); mode[1]=1 if edge_index is int64 (else int32)
__global__ void probe_kernel(const u32* __restrict__ xw, const int* __restrict__ ei,
                             int* __restrict__ mode){
    if(threadIdx.x==0 && blockIdx.x==0){
        int insane = 0;
        for(int i=0;i<64;i++){
            u32 w  = xw[i];
            u32 lo = w & 0xffffu;          // bf16: element 2i ; f32: low mantissa half
            u32 e  = (lo >> 7) & 0xff;
            if(lo != 0 && (e < 48 || e > 208)) insane++;
        }
        mode[0] = (insane > 8) ? 1 : 0;
        int zeros = 0;
        for(int i=0;i<16;i++) if(ei[2*i+1]==0) zeros++;
        mode[1] = (zeros==16) ? 1 : 0;
    }
}

__device__ __forceinline__ int ld_src(const int* ei, int i64f, int e){
    return i64f ? ei[2*e] : ei[e];
}
__device__ __forceinline__ int ld_dst(const int* ei, int i64f, int e){
    return i64f ? ei[2*(NE + e)] : ei[NE + e];
}

// ---------------- CSR build ----------------
__global__ void hist_kernel(const int* __restrict__ ei, int* __restrict__ deg,
                            const int* __restrict__ mode){
    int e = blockIdx.x*256 + threadIdx.x;
    int i64f = mode[1];
    if(e < NE) atomicAdd(&deg[ld_dst(ei, i64f, e)], 1);
}

__global__ void scan_kernel(const int* __restrict__ deg, int* __restrict__ rp,
                            int* __restrict__ cur, int M){
    __shared__ int part[1024];
    int t = threadIdx.x;
    int CH = (M + 1023) >> 10;
    int lo = t*CH, hi = min(lo+CH, M);
    int s = 0;
    for(int i=lo;i<hi;i++) s += deg[i];
    part[t] = s;
    __syncthreads();
    for(int o=1;o<1024;o<<=1){
        int add = (t>=o) ? part[t-o] : 0;
        __syncthreads();
        part[t] += add;
        __syncthreads();
    }
    int run = (t>0) ? part[t-1] : 0;
    for(int i=lo;i<hi;i++){ rp[i]=run; cur[i]=run; run += deg[i]; }
    if(t==1023) rp[M] = part[1023];
}

__global__ void fill_kernel(const int* __restrict__ ei, int* __restrict__ cur,
                            int* __restrict__ ssrc, const int* __restrict__ mode){
    int e = blockIdx.x*256 + threadIdx.x;
    int i64f = mode[1];
    if(e < NE){
        int d = ld_dst(ei, i64f, e);
        int pos = atomicAdd(&cur[d], 1);
        ssrc[pos] = ld_src(ei, i64f, e);
    }
}

// ---------------- canonicalization (everything -> bf16) ----------------
__global__ void cvt_x(const float* __restrict__ xf, u16* __restrict__ Xc,
                      const int* __restrict__ mode){
    if(!mode[0]) return;  // already bf16; agg will read original directly
    size_t i = ((size_t)blockIdx.x*256 + threadIdx.x)*8;
    float4 a = *(const float4*)(xf+i);
    float4 b = *(const float4*)(xf+i+4);
    u16 o[8] = {f2b(a.x),f2b(a.y),f2b(a.z),f2b(a.w),
                f2b(b.x),f2b(b.y),f2b(b.z),f2b(b.w)};
    uint4 pk;
    pk.x = (u32)o[0] | ((u32)o[1]<<16);
    pk.y = (u32)o[2] | ((u32)o[3]<<16);
    pk.z = (u32)o[4] | ((u32)o[5]<<16);
    pk.w = (u32)o[6] | ((u32)o[7]<<16);
    *(uint4*)(Xc + i) = pk;
}

// W: KxN (f32 or bf16) -> Wt: NxK bf16
__global__ void transpose_cvt(const void* __restrict__ W, u16* __restrict__ Wt,
                              int K, int N, const int* __restrict__ mode){
    int id = blockIdx.x*256 + threadIdx.x;
    if(id < K*N){
        int k = id / N, n = id % N;
        float v = mode[0] ? ((const float*)W)[id] : b2f(((const u16*)W)[id]);
        Wt[n*K + k] = f2b(v);
    }
}

__global__ void cvt_wfc(const void* __restrict__ W, u16* __restrict__ Wc,
                        const int* __restrict__ mode){
    int id = blockIdx.x*256 + threadIdx.x;   // < DIM*NC = 4096
    float v = mode[0] ? ((const float*)W)[id] : b2f(((const u16*)W)[id]);
    Wc[id] = f2b(v);
}

// 11 small vectors -> Vc (each at slot*256)
__global__ void cvt_vecs(const void* p0, const void* p1, const void* p2, const void* p3,
                         const void* p4, const void* p5, const void* p6, const void* p7,
                         const void* p8, const void* p9, const void* p10,
                         u16* __restrict__ Vc, const int* __restrict__ mode){
    const void* ps[11] = {p0,p1,p2,p3,p4,p5,p6,p7,p8,p9,p10};
    int lens[11] = {DIM,DIM,DIM,DIM,DIM,DIM,DIM,DIM,DIM,DIM,NC};
    int b = blockIdx.x, t = threadIdx.x;
    if(t < lens[b]){
        float v = mode[0] ? ((const float*)ps[b])[t] : b2f(((const u16*)ps[b])[t]);
        Vc[b*256 + t] = f2b(v);
    }
}

// ---------------- aggregation: out[i] = h[i] + sum_{e in row i} h[src[e]] ----------------
template<int VEC>
__global__ __launch_bounds__(256) void agg_kernel(const u16* __restrict__ hA,
        const u16* __restrict__ hB, const int* __restrict__ mode,
        const int* __restrict__ rp, const int* __restrict__ ssrc,
        u16* __restrict__ out, int M){
    const int F = 64*VEC;
    int node = blockIdx.x*4 + (threadIdx.x>>6);
    if(node >= M) return;
    const u16* h = mode[0] ? hB : hA;   // f32 underlying -> use canonical copy
    int lane = threadIdx.x & 63;
    float acc[VEC];
    const u16* bp = h + (size_t)node*F + lane*VEC;
    if(VEC==4){
        uint2 u = *(const uint2*)bp;
        acc[0]=lo16(u.x); acc[1]=hi16(u.x); acc[2]=lo16(u.y); acc[3]=hi16(u.y);
    } else {
        u32 u = *(const u32*)bp;
        acc[0]=lo16(u); acc[1]=hi16(u);
    }
    int e0 = rp[node], e1 = rp[node+1];
    for(int e=e0;e<e1;e++){
        int s = ssrc[e];
        const u16* sp = h + (size_t)s*F + lane*VEC;
        if(VEC==4){
            uint2 u = *(const uint2*)sp;
            acc[0]+=lo16(u.x); acc[1]+=hi16(u.x); acc[2]+=lo16(u.y); acc[3]+=hi16(u.y);
        } else {
            u32 u = *(const u32*)sp;
            acc[0]+=lo16(u); acc[1]+=hi16(u);
        }
    }
    u16* op = out + (size_t)node*F + lane*VEC;
    if(VEC==4){
        uint2 o;
        o.x = (u32)f2b(acc[0]) | ((u32)f2b(acc[1])<<16);
        o.y = (u32)f2b(acc[2]) | ((u32)f2b(acc[3])<<16);
        *(uint2*)op = o;
    } else {
        *(u32*)op = (u32)f2b(acc[0]) | ((u32)f2b(acc[1])<<16);
    }
}

// ---------------- MFMA GEMM: C = act(A[MxK] @ W[KxN] + bias), W transposed (NxK) ----------------
#define BM 64
#define BN 64
#define BK 32
__global__ __launch_bounds__(256) void gemm_bias_act(
        const u16* __restrict__ A, const u16* __restrict__ Bt,
        const u16* __restrict__ bias, u16* __restrict__ C,
        int M, int N, int K, int do_relu){
    __shared__ __align__(16) u16 lA[BM*BK];
    __shared__ __align__(16) u16 lB[BN*BK];
    int tid = threadIdx.x;
    int wave = tid>>6, lane = tid&63;
    int q = lane>>4, mr = lane&15;
    int m0 = blockIdx.x*BM, n0 = blockIdx.y*BN;
    int srow = tid>>2;            // 0..63
    int soff = (tid&3)*8;         // element offset, 16B chunks
    f32x4 acc[4];
    for(int c=0;c<4;c++) acc[c] = (f32x4){0.f,0.f,0.f,0.f};

    for(int k0=0;k0<K;k0+=BK){
        uint4 av;
        int gr = m0 + srow;
        if(gr < M) av = *(const uint4*)(A + (size_t)gr*K + k0 + soff);
        else       av = make_uint4(0,0,0,0);
        *(uint4*)(&lA[srow*BK + soff]) = av;
        *(uint4*)(&lB[srow*BK + soff]) = *(const uint4*)(Bt + (size_t)(n0+srow)*K + k0 + soff);
        __syncthreads();
        bf16x8 af = *reinterpret_cast<const bf16x8*>(&lA[(wave*16+mr)*BK + q*8]);
        #pragma unroll
        for(int c=0;c<4;c++){
            bf16x8 bf = *reinterpret_cast<const bf16x8*>(&lB[(c*16+mr)*BK + q*8]);
            acc[c] = __builtin_amdgcn_mfma_f32_16x16x32_bf16(af, bf, acc[c], 0, 0, 0);
        }
        __syncthreads();
    }
    #pragma unroll
    for(int c=0;c<4;c++){
        int col = n0 + c*16 + mr;
        float bv = b2f(bias[col]);
        #pragma unroll
        for(int r=0;r<4;r++){
            int row = m0 + wave*16 + q*4 + r;
            if(row < M){
                float v = acc[c][r] + bv;
                if(do_relu) v = fmaxf(v, 0.f);
                C[(size_t)row*N + col] = f2b(v);
            }
        }
    }
}

// ---------------- BatchNorm ----------------
__global__ __launch_bounds__(256) void bn_stats(const u16* __restrict__ h,
        float* __restrict__ stats, int M){
    int f = threadIdx.x;
    int r0 = blockIdx.x*512, r1 = min(r0+512, M);
    float s=0.f, s2=0.f;
    for(int r=r0;r<r1;r++){
        float v = b2f(h[(size_t)r*DIM + f]);
        s += v; s2 += v*v;
    }
    atomicAdd(&stats[f], s);
    atomicAdd(&stats[DIM+f], s2);
}

__global__ __launch_bounds__(256) void bn_apply(u16* __restrict__ h,
        const float* __restrict__ stats, const u16* __restrict__ g,
        const u16* __restrict__ be, int M){
    size_t idx = (size_t)blockIdx.x*256 + threadIdx.x;
    if(idx >= (size_t)M*DIM) return;
    int f = (int)(idx & (DIM-1));
    float inv_m = 1.0f / (float)M;
    float mean = stats[f] * inv_m;
    float var  = fmaxf(stats[DIM+f] * inv_m - mean*mean, 0.f);
    float rstd = rsqrtf(var + 1e-5f);
    float v = b2f(h[idx]);
    h[idx] = f2b(b2f(g[f]) * (v - mean) * rstd + b2f(be[f]));
}

// ---------------- FC (256->16) + log_softmax ----------------
__global__ __launch_bounds__(256) void fc_lsm(const u16* __restrict__ h,
        const u16* __restrict__ wfc, const u16* __restrict__ bfc,
        void* __restrict__ out, const int* __restrict__ mode, int M){
    __shared__ float lds[256];
    __shared__ float rmx[16], rls[16];
    int tid = threadIdx.x;
    int r = tid>>4, c = tid&15;
    int row = blockIdx.x*16 + r;
    float acc = b2f(bfc[c]);
    const u16* hp = h + (size_t)row*DIM;
    for(int k=0;k<DIM;k++) acc += b2f(hp[k]) * b2f(wfc[k*NC + c]);
    lds[tid] = acc;
    __syncthreads();
    if(c==0){
        float mx = -1e30f;
        for(int i=0;i<NC;i++) mx = fmaxf(mx, lds[r*NC+i]);
        float s = 0.f;
        for(int i=0;i<NC;i++) s += expf(lds[r*NC+i] - mx);
        rmx[r] = mx; rls[r] = logf(s);
    }
    __syncthreads();
    if(row < M){
        float v = acc - rmx[r] - rls[r];
        if(mode[0]) ((float*)out)[(size_t)row*NC + c] = v;
        else        ((u16*)out)[(size_t)row*NC + c] = f2b(v);
    }
}

extern "C" void kernel_launch(void* const* d_in, const int* in_sizes, int n_in,
                              void* d_out, int out_size, void* d_ws, size_t ws_size,
                              hipStream_t stream){
    const void* x   = d_in[0];
    const int*  ei  = (const int*)d_in[1];
    const void* w1a = d_in[2];  const void* b1a = d_in[3];
    const void* w1b = d_in[4];  const void* b1b = d_in[5];
    const void* g1  = d_in[6];  const void* be1 = d_in[7];
    const void* w2a = d_in[8];  const void* b2a = d_in[9];
    const void* w2b = d_in[10]; const void* b2b = d_in[11];
    const void* g2  = d_in[12]; const void* be2 = d_in[13];
    const void* w3a = d_in[14]; const void* b3a = d_in[15];
    const void* w3b = d_in[16]; const void* b3b = d_in[17];
    const void* wfc = d_in[18]; const void* bfc = d_in[19];

    char* base = (char*)d_ws;
    size_t off = 0;
    auto alloc = [&](size_t bytes)->void*{
        void* p = base + off;
        off = (off + bytes + 255) & ~(size_t)255;
        return p;
    };
    u16*  P     = (u16*)alloc((size_t)NND*DIM*2);   // also aliases Xc (canonical x)
    u16*  Q     = (u16*)alloc((size_t)NND*DIM*2);
    int*  ssrc  = (int*)alloc((size_t)NE*4);
    int*  deg   = (int*)alloc((size_t)NND*4);
    int*  rp    = (int*)alloc((size_t)(NND+1)*4);
    int*  cur   = (int*)alloc((size_t)NND*4);
    float* stats= (float*)alloc(2*DIM*4);
    int*  mode  = (int*)alloc(16);
    u16* Wt1a = (u16*)alloc((size_t)F0*DIM*2);
    u16* Wt1b = (u16*)alloc((size_t)DIM*DIM*2);
    u16* Wt2a = (u16*)alloc((size_t)DIM*DIM*2);
    u16* Wt2b = (u16*)alloc((size_t)DIM*DIM*2);
    u16* Wt3a = (u16*)alloc((size_t)DIM*DIM*2);
    u16* Wt3b = (u16*)alloc((size_t)DIM*DIM*2);
    u16* Vc   = (u16*)alloc(11*256*2);
    u16* Wfc  = (u16*)alloc((size_t)DIM*NC*2);
    u16* Xc   = P;  // alias: consumed by layer-1 agg before P is first written

    // dtype probe (decides f32-vs-bf16 and int64-vs-int32 on-device)
    probe_kernel<<<1, 64, 0, stream>>>((const u32*)x, ei, mode);

    // CSR build
    hipMemsetAsync(deg, 0, (size_t)NND*4, stream);
    hist_kernel<<<NE/256, 256, 0, stream>>>(ei, deg, mode);
    scan_kernel<<<1, 1024, 0, stream>>>(deg, rp, cur, NND);
    fill_kernel<<<NE/256, 256, 0, stream>>>(ei, cur, ssrc, mode);

    // canonicalize params (and x if f32)
    cvt_x<<<(NND*F0)/(256*8), 256, 0, stream>>>((const float*)x, Xc, mode);
    transpose_cvt<<<(F0*DIM+255)/256, 256, 0, stream>>>(w1a, Wt1a, F0, DIM, mode);
    transpose_cvt<<<(DIM*DIM+255)/256, 256, 0, stream>>>(w1b, Wt1b, DIM, DIM, mode);
    transpose_cvt<<<(DIM*DIM+255)/256, 256, 0, stream>>>(w2a, Wt2a, DIM, DIM, mode);
    transpose_cvt<<<(DIM*DIM+255)/256, 256, 0, stream>>>(w2b, Wt2b, DIM, DIM, mode);
    transpose_cvt<<<(DIM*DIM+255)/256, 256, 0, stream>>>(w3a, Wt3a, DIM, DIM, mode);
    transpose_cvt<<<(DIM*DIM+255)/256, 256, 0, stream>>>(w3b, Wt3b, DIM, DIM, mode);
    cvt_wfc<<<(DIM*NC)/256, 256, 0, stream>>>(wfc, Wfc, mode);
    cvt_vecs<<<11, 256, 0, stream>>>(b1a,b1b,g1,be1,b2a,b2b,g2,be2,b3a,b3b,bfc, Vc, mode);

    dim3 ggrid((NND+BM-1)/BM, DIM/BN);

    // ---- layer 1 ----
    agg_kernel<2><<<NND/4, 256, 0, stream>>>((const u16*)x, Xc, mode, rp, ssrc, Q, NND);
    gemm_bias_act<<<ggrid, 256, 0, stream>>>(Q, Wt1a, Vc+0*256, P, NND, DIM, F0, 1);
    gemm_bias_act<<<ggrid, 256, 0, stream>>>(P, Wt1b, Vc+1*256, Q, NND, DIM, DIM, 1);
    hipMemsetAsync(stats, 0, 2*DIM*4, stream);
    bn_stats<<<(NND+511)/512, 256, 0, stream>>>(Q, stats, NND);
    bn_apply<<<(NND*DIM)/256, 256, 0, stream>>>(Q, stats, Vc+2*256, Vc+3*256, NND);

    // ---- layer 2 ----
    agg_kernel<4><<<NND/4, 256, 0, stream>>>(Q, Q, mode, rp, ssrc, P, NND);
    gemm_bias_act<<<ggrid, 256, 0, stream>>>(P, Wt2a, Vc+4*256, Q, NND, DIM, DIM, 1);
    gemm_bias_act<<<ggrid, 256, 0, stream>>>(Q, Wt2b, Vc+5*256, P, NND, DIM, DIM, 1);
    hipMemsetAsync(stats, 0, 2*DIM*4, stream);
    bn_stats<<<(NND+511)/512, 256, 0, stream>>>(P, stats, NND);
    bn_apply<<<(NND*DIM)/256, 256, 0, stream>>>(P, stats, Vc+6*256, Vc+7*256, NND);

    // ---- layer 3 ----
    agg_kernel<4><<<NND/4, 256, 0, stream>>>(P, P, mode, rp, ssrc, Q, NND);
    gemm_bias_act<<<ggrid, 256, 0, stream>>>(Q, Wt3a, Vc+8*256, P, NND, DIM, DIM, 1);
    gemm_bias_act<<<ggrid, 256, 0, stream>>>(P, Wt3b, Vc+9*256, Q, NND, DIM, DIM, 1);

    // ---- FC + log_softmax ----
    fc_lsm<<<NND/16, 256, 0, stream>>>(Q, Wfc, Vc+10*256, d_out, mode, NND);
}

// Round 3
// 1911.531 us; speedup vs baseline: 1.1742x; 1.1742x over previous
//
#include <hip/hip_runtime.h>

typedef unsigned int  u32;
typedef unsigned short u16;

#define NND 100000
#define MPAD 100096   // 782*128, so the 128-row GEMM tiles need no M guards
#define NE  3200000
#define F0  128
#define DIM 256
#define NC  16

typedef __bf16 bf16x8 __attribute__((ext_vector_type(8)));
typedef float  f32x4  __attribute__((ext_vector_type(4)));

__device__ __forceinline__ float b2f(u16 h){ return __uint_as_float(((u32)h)<<16); }
__device__ __forceinline__ u16 f2b(float f){
    u32 u = __float_as_uint(f);
    return (u16)((u + 0x7fffu + ((u>>16)&1u)) >> 16);
}
__device__ __forceinline__ float lo16(u32 u){ return __uint_as_float(u<<16); }
__device__ __forceinline__ float hi16(u32 u){ return __uint_as_float(u & 0xffff0000u); }

__device__ __forceinline__ void gload16(const u16* g, u16* l){
    __builtin_amdgcn_global_load_lds(
        (const __attribute__((address_space(1))) u32*)g,
        (__attribute__((address_space(3))) u32*)l, 16, 0, 0);
}

// ---------------- dtype probe ----------------
// mode[0]=1 if floats are f32 (else bf16); mode[1]=1 if edge_index is int64 (else int32)
__global__ void probe_kernel(const u32* __restrict__ xw, const int* __restrict__ ei,
                             int* __restrict__ mode){
    if(threadIdx.x==0 && blockIdx.x==0){
        int insane = 0;
        for(int i=0;i<64;i++){
            u32 w  = xw[i];
            u32 lo = w & 0xffffu;
            u32 e  = (lo >> 7) & 0xff;
            if(lo != 0 && (e < 48 || e > 208)) insane++;
        }
        mode[0] = (insane > 8) ? 1 : 0;
        int zeros = 0;
        for(int i=0;i<16;i++) if(ei[2*i+1]==0) zeros++;
        mode[1] = (zeros==16) ? 1 : 0;
    }
}

__device__ __forceinline__ int ld_src(const int* ei, int i64f, int e){
    return i64f ? ei[2*e] : ei[e];
}
__device__ __forceinline__ int ld_dst(const int* ei, int i64f, int e){
    return i64f ? ei[2*(NE + e)] : ei[NE + e];
}

// ---------------- CSR build ----------------
__global__ void hist_kernel(const int* __restrict__ ei, int* __restrict__ deg,
                            const int* __restrict__ mode){
    int e = blockIdx.x*256 + threadIdx.x;
    int i64f = mode[1];
    if(e < NE) atomicAdd(&deg[ld_dst(ei, i64f, e)], 1);
}

__global__ void scan_kernel(const int* __restrict__ deg, int* __restrict__ rp,
                            int* __restrict__ cur, int M){
    __shared__ int part[1024];
    int t = threadIdx.x;
    int CH = (M + 1023) >> 10;
    int lo = t*CH, hi = min(lo+CH, M);
    int s = 0;
    for(int i=lo;i<hi;i++) s += deg[i];
    part[t] = s;
    __syncthreads();
    for(int o=1;o<1024;o<<=1){
        int add = (t>=o) ? part[t-o] : 0;
        __syncthreads();
        part[t] += add;
        __syncthreads();
    }
    int run = (t>0) ? part[t-1] : 0;
    for(int i=lo;i<hi;i++){ rp[i]=run; cur[i]=run; run += deg[i]; }
    if(t==1023) rp[M] = part[1023];
}

__global__ void fill_kernel(const int* __restrict__ ei, int* __restrict__ cur,
                            int* __restrict__ ssrc, const int* __restrict__ mode){
    int e = blockIdx.x*256 + threadIdx.x;
    int i64f = mode[1];
    if(e < NE){
        int d = ld_dst(ei, i64f, e);
        int pos = atomicAdd(&cur[d], 1);
        ssrc[pos] = ld_src(ei, i64f, e);
    }
}

// ---------------- canonicalization (everything -> bf16) ----------------
__global__ void cvt_x(const float* __restrict__ xf, u16* __restrict__ Xc,
                      const int* __restrict__ mode){
    if(!mode[0]) return;
    size_t i = ((size_t)blockIdx.x*256 + threadIdx.x)*8;
    float4 a = *(const float4*)(xf+i);
    float4 b = *(const float4*)(xf+i+4);
    uint4 pk;
    pk.x = (u32)f2b(a.x) | ((u32)f2b(a.y)<<16);
    pk.y = (u32)f2b(a.z) | ((u32)f2b(a.w)<<16);
    pk.z = (u32)f2b(b.x) | ((u32)f2b(b.y)<<16);
    pk.w = (u32)f2b(b.z) | ((u32)f2b(b.w)<<16);
    *(uint4*)(Xc + i) = pk;
}

// W: KxN (f32 or bf16) -> Wt: NxK bf16
__global__ void transpose_cvt(const void* __restrict__ W, u16* __restrict__ Wt,
                              int K, int N, const int* __restrict__ mode){
    int id = blockIdx.x*256 + threadIdx.x;
    if(id < K*N){
        int k = id / N, n = id % N;
        float v = mode[0] ? ((const float*)W)[id] : b2f(((const u16*)W)[id]);
        Wt[n*K + k] = f2b(v);
    }
}

// wfc: (DIM x NC) -> WfcT: (NC x DIM) bf16
__global__ void cvt_wfc(const void* __restrict__ W, u16* __restrict__ Wc,
                        const int* __restrict__ mode){
    int id = blockIdx.x*256 + threadIdx.x;   // < DIM*NC = 4096
    int k = id / NC, c = id % NC;
    float v = mode[0] ? ((const float*)W)[id] : b2f(((const u16*)W)[id]);
    Wc[c*DIM + k] = f2b(v);
}

// 11 small vectors -> Vc (each at slot*256)
__global__ void cvt_vecs(const void* p0, const void* p1, const void* p2, const void* p3,
                         const void* p4, const void* p5, const void* p6, const void* p7,
                         const void* p8, const void* p9, const void* p10,
                         u16* __restrict__ Vc, const int* __restrict__ mode){
    const void* ps[11] = {p0,p1,p2,p3,p4,p5,p6,p7,p8,p9,p10};
    int lens[11] = {DIM,DIM,DIM,DIM,DIM,DIM,DIM,DIM,DIM,DIM,NC};
    int b = blockIdx.x, t = threadIdx.x;
    if(t < lens[b]){
        float v = mode[0] ? ((const float*)ps[b])[t] : b2f(((const u16*)ps[b])[t]);
        Vc[b*256 + t] = f2b(v);
    }
}

// ---------------- aggregation (+ fused BN affine of the PREVIOUS layer) ----------------
// out[i] = affine( h[i] + sum_{e in row i} h[src[e]] )
// where affine folds BN: sum of (a*h_j + b) = a*sum(h_j) + (deg+1)*b
template<int VEC>
__global__ __launch_bounds__(256) void agg_kernel(const u16* __restrict__ hA,
        const u16* __restrict__ hB, const int* __restrict__ mode,
        const int* __restrict__ rp, const int* __restrict__ ssrc,
        u16* __restrict__ out,
        const float* __restrict__ stats, const u16* __restrict__ g,
        const u16* __restrict__ be, int use_bn, int M){
    const int F = 64*VEC;
    int node = blockIdx.x*4 + (threadIdx.x>>6);
    if(node >= M) return;
    int lane = threadIdx.x & 63;
    int lv = lane*VEC;
    const u16* h = (VEC==2 && mode[0]) ? hB : hA;

    float acc[VEC];
    {   // self row
        const u16* bp = h + (size_t)node*F + lv;
        if(VEC==4){
            uint2 u = *(const uint2*)bp;
            acc[0]=lo16(u.x); acc[1]=hi16(u.x); acc[2]=lo16(u.y); acc[3]=hi16(u.y);
        } else {
            u32 u = *(const u32*)bp;
            acc[0]=lo16(u); acc[1]=hi16(u);
        }
    }

    auto gather4 = [&](int s0,int s1,int s2,int s3){
        const u16* p0 = h + (size_t)s0*F + lv;
        const u16* p1 = h + (size_t)s1*F + lv;
        const u16* p2 = h + (size_t)s2*F + lv;
        const u16* p3 = h + (size_t)s3*F + lv;
        if(VEC==4){
            uint2 u0=*(const uint2*)p0, u1=*(const uint2*)p1,
                  u2=*(const uint2*)p2, u3=*(const uint2*)p3;
            acc[0]+=lo16(u0.x)+lo16(u1.x)+lo16(u2.x)+lo16(u3.x);
            acc[1]+=hi16(u0.x)+hi16(u1.x)+hi16(u2.x)+hi16(u3.x);
            acc[2]+=lo16(u0.y)+lo16(u1.y)+lo16(u2.y)+lo16(u3.y);
            acc[3]+=hi16(u0.y)+hi16(u1.y)+hi16(u2.y)+hi16(u3.y);
        } else {
            u32 u0=*(const u32*)p0, u1=*(const u32*)p1,
                u2=*(const u32*)p2, u3=*(const u32*)p3;
            acc[0]+=lo16(u0)+lo16(u1)+lo16(u2)+lo16(u3);
            acc[1]+=hi16(u0)+hi16(u1)+hi16(u2)+hi16(u3);
        }
    };

    int e0 = rp[node], e1 = rp[node+1];
    int e = e0;
    int eend = e0 + ((e1-e0) & ~3);
    if(e < eend){
        int s0=ssrc[e+0], s1=ssrc[e+1], s2=ssrc[e+2], s3=ssrc[e+3];
        e += 4;
        for(; e < eend; e += 4){
            int t0=ssrc[e+0], t1=ssrc[e+1], t2=ssrc[e+2], t3=ssrc[e+3];
            gather4(s0,s1,s2,s3);
            s0=t0; s1=t1; s2=t2; s3=t3;
        }
        gather4(s0,s1,s2,s3);
    }
    for(; e<e1; e++){
        int s = ssrc[e];
        const u16* sp = h + (size_t)s*F + lv;
        if(VEC==4){
            uint2 u = *(const uint2*)sp;
            acc[0]+=lo16(u.x); acc[1]+=hi16(u.x); acc[2]+=lo16(u.y); acc[3]+=hi16(u.y);
        } else {
            u32 u = *(const u32*)sp;
            acc[0]+=lo16(u); acc[1]+=hi16(u);
        }
    }

    float aff_a[VEC], aff_b[VEC];
    if(use_bn){
        float inv_m = 1.0f / (float)M;
        #pragma unroll
        for(int v=0; v<VEC; v++){
            int f = lv + v;
            float mean = stats[f]*inv_m;
            float var  = fmaxf(stats[F+f]*inv_m - mean*mean, 0.f);
            float rstd = rsqrtf(var + 1e-5f);
            float gg = b2f(g[f]);
            aff_a[v] = gg*rstd;
            aff_b[v] = b2f(be[f]) - gg*rstd*mean;
        }
    } else {
        #pragma unroll
        for(int v=0; v<VEC; v++){ aff_a[v]=1.f; aff_b[v]=0.f; }
    }
    float cnt = (float)(e1-e0+1);

    u16* op = out + (size_t)node*F + lv;
    if(VEC==4){
        uint2 o;
        float r0 = aff_a[0]*acc[0] + cnt*aff_b[0];
        float r1 = aff_a[1]*acc[1] + cnt*aff_b[1];
        float r2 = aff_a[2]*acc[2] + cnt*aff_b[2];
        float r3 = aff_a[3]*acc[3] + cnt*aff_b[3];
        o.x = (u32)f2b(r0) | ((u32)f2b(r1)<<16);
        o.y = (u32)f2b(r2) | ((u32)f2b(r3)<<16);
        *(uint2*)op = o;
    } else {
        float r0 = aff_a[0]*acc[0] + cnt*aff_b[0];
        float r1 = aff_a[1]*acc[1] + cnt*aff_b[1];
        *(u32*)op = (u32)f2b(r0) | ((u32)f2b(r1)<<16);
    }
}

// ---------------- MFMA GEMM, 128x128 tile, global_load_lds staging (m97 structure) ----
// C = act(A[MPADxK] @ W[KxN] + bias); W given transposed (NxK). No M guards (padded).
#define TBM 128
#define TBN 128
#define TBK 32
__global__ __launch_bounds__(256) void gemm128(
        const u16* __restrict__ A, const u16* __restrict__ Bt,
        const u16* __restrict__ bias, u16* __restrict__ C,
        int N, int K, int do_relu){
    __shared__ __align__(16) u16 lA[TBM*TBK];
    __shared__ __align__(16) u16 lB[TBN*TBK];
    int tid = threadIdx.x;
    int w = tid>>6, lane = tid&63;
    int q = lane>>4, mr = lane&15;
    int wr = w>>1, wc = w&1;
    int m0 = blockIdx.x*TBM, n0 = blockIdx.y*TBN;

    f32x4 acc[4][4];
    #pragma unroll
    for(int i=0;i<4;i++)
        #pragma unroll
        for(int c=0;c<4;c++) acc[i][c] = (f32x4){0.f,0.f,0.f,0.f};

    // staging pointers: wave w stages A rows [w*32, w*32+32) and B rows [w*32, w*32+32)
    const u16* ga0 = A  + (size_t)(m0 + w*32 + (lane>>2))*K + (lane&3)*8;
    const u16* ga1 = ga0 + (size_t)16*K;
    const u16* gb0 = Bt + (size_t)(n0 + w*32 + (lane>>2))*K + (lane&3)*8;
    const u16* gb1 = gb0 + (size_t)16*K;
    u16* la0 = &lA[(w*32)*TBK];    u16* la1 = la0 + 16*TBK;
    u16* lb0 = &lB[(w*32)*TBK];    u16* lb1 = lb0 + 16*TBK;

    for(int k0=0; k0<K; k0+=TBK){
        gload16(ga0, la0); gload16(ga1, la1);
        gload16(gb0, lb0); gload16(gb1, lb1);
        ga0 += TBK; ga1 += TBK; gb0 += TBK; gb1 += TBK;
        __syncthreads();
        bf16x8 af[4], bfr[4];
        #pragma unroll
        for(int i=0;i<4;i++)
            af[i] = *reinterpret_cast<const bf16x8*>(&lA[(wr*64 + i*16 + mr)*TBK + q*8]);
        #pragma unroll
        for(int c=0;c<4;c++)
            bfr[c] = *reinterpret_cast<const bf16x8*>(&lB[(wc*64 + c*16 + mr)*TBK + q*8]);
        #pragma unroll
        for(int i=0;i<4;i++)
            #pragma unroll
            for(int c=0;c<4;c++)
                acc[i][c] = __builtin_amdgcn_mfma_f32_16x16x32_bf16(af[i], bfr[c], acc[i][c], 0, 0, 0);
        __syncthreads();
    }

    #pragma unroll
    for(int c=0;c<4;c++){
        int col = n0 + wc*64 + c*16 + mr;
        float bv = b2f(bias[col]);
        #pragma unroll
        for(int i=0;i<4;i++){
            int row = m0 + wr*64 + i*16 + q*4;
            #pragma unroll
            for(int r=0;r<4;r++){
                float v = acc[i][c][r] + bv;
                if(do_relu) v = fmaxf(v, 0.f);
                C[(size_t)(row + r)*N + col] = f2b(v);
            }
        }
    }
}

// ---------------- BatchNorm stats ----------------
__global__ __launch_bounds__(256) void bn_stats(const u16* __restrict__ h,
        float* __restrict__ stats, int M){
    int f = threadIdx.x;
    int r0 = blockIdx.x*512, r1 = min(r0+512, M);
    float s=0.f, s2=0.f;
    for(int r=r0;r<r1;r++){
        float v = b2f(h[(size_t)r*DIM + f]);
        s += v; s2 += v*v;
    }
    atomicAdd(&stats[f], s);
    atomicAdd(&stats[DIM+f], s2);
}

// ---------------- FC (256->16) + log_softmax; wfc pre-transposed (NC x DIM) -------
__global__ __launch_bounds__(256) void fc_lsm(const u16* __restrict__ h,
        const u16* __restrict__ wfcT, const u16* __restrict__ bfc,
        void* __restrict__ out, const int* __restrict__ mode, int M){
    __shared__ float lds[256];
    __shared__ float rmx[16], rls[16];
    int tid = threadIdx.x;
    int r = tid>>4, c = tid&15;
    int row = blockIdx.x*16 + r;
    float acc = b2f(bfc[c]);
    const u16* hp = h + (size_t)row*DIM;
    const u16* wp = wfcT + c*DIM;
    for(int k=0;k<DIM;k+=8){
        uint4 hv = *(const uint4*)(hp+k);
        uint4 wv = *(const uint4*)(wp+k);
        acc += lo16(hv.x)*lo16(wv.x) + hi16(hv.x)*hi16(wv.x)
             + lo16(hv.y)*lo16(wv.y) + hi16(hv.y)*hi16(wv.y)
             + lo16(hv.z)*lo16(wv.z) + hi16(hv.z)*hi16(wv.z)
             + lo16(hv.w)*lo16(wv.w) + hi16(hv.w)*hi16(wv.w);
    }
    lds[tid] = acc;
    __syncthreads();
    if(c==0){
        float mx = -1e30f;
        for(int i=0;i<NC;i++) mx = fmaxf(mx, lds[r*NC+i]);
        float s = 0.f;
        for(int i=0;i<NC;i++) s += expf(lds[r*NC+i] - mx);
        rmx[r] = mx; rls[r] = logf(s);
    }
    __syncthreads();
    if(row < M){
        float v = acc - rmx[r] - rls[r];
        if(mode[0]) ((float*)out)[(size_t)row*NC + c] = v;
        else        ((u16*)out)[(size_t)row*NC + c] = f2b(v);
    }
}

extern "C" void kernel_launch(void* const* d_in, const int* in_sizes, int n_in,
                              void* d_out, int out_size, void* d_ws, size_t ws_size,
                              hipStream_t stream){
    const void* x   = d_in[0];
    const int*  ei  = (const int*)d_in[1];
    const void* w1a = d_in[2];  const void* b1a = d_in[3];
    const void* w1b = d_in[4];  const void* b1b = d_in[5];
    const void* g1  = d_in[6];  const void* be1 = d_in[7];
    const void* w2a = d_in[8];  const void* b2a = d_in[9];
    const void* w2b = d_in[10]; const void* b2b = d_in[11];
    const void* g2  = d_in[12]; const void* be2 = d_in[13];
    const void* w3a = d_in[14]; const void* b3a = d_in[15];
    const void* w3b = d_in[16]; const void* b3b = d_in[17];
    const void* wfc = d_in[18]; const void* bfc = d_in[19];

    char* base = (char*)d_ws;
    size_t off = 0;
    auto alloc = [&](size_t bytes)->void*{
        void* p = base + off;
        off = (off + bytes + 255) & ~(size_t)255;
        return p;
    };
    u16*  P     = (u16*)alloc((size_t)MPAD*DIM*2);   // also aliases Xc
    u16*  Q     = (u16*)alloc((size_t)MPAD*DIM*2);
    int*  ssrc  = (int*)alloc((size_t)NE*4);
    int*  deg   = (int*)alloc((size_t)NND*4);
    int*  rp    = (int*)alloc((size_t)(NND+1)*4);
    int*  cur   = (int*)alloc((size_t)NND*4);
    float* stats= (float*)alloc(2*DIM*4);
    int*  mode  = (int*)alloc(16);
    u16* Wt1a = (u16*)alloc((size_t)F0*DIM*2);
    u16* Wt1b = (u16*)alloc((size_t)DIM*DIM*2);
    u16* Wt2a = (u16*)alloc((size_t)DIM*DIM*2);
    u16* Wt2b = (u16*)alloc((size_t)DIM*DIM*2);
    u16* Wt3a = (u16*)alloc((size_t)DIM*DIM*2);
    u16* Wt3b = (u16*)alloc((size_t)DIM*DIM*2);
    u16* Vc   = (u16*)alloc(11*256*2);
    u16* Wfc  = (u16*)alloc((size_t)DIM*NC*2);
    u16* Xc   = P;  // consumed by layer-1 agg before P is first written

    probe_kernel<<<1, 64, 0, stream>>>((const u32*)x, ei, mode);

    // CSR build
    hipMemsetAsync(deg, 0, (size_t)NND*4, stream);
    hist_kernel<<<NE/256, 256, 0, stream>>>(ei, deg, mode);
    scan_kernel<<<1, 1024, 0, stream>>>(deg, rp, cur, NND);
    fill_kernel<<<NE/256, 256, 0, stream>>>(ei, cur, ssrc, mode);

    // canonicalize params (and x if f32)
    cvt_x<<<(NND*F0)/(256*8), 256, 0, stream>>>((const float*)x, Xc, mode);
    transpose_cvt<<<(F0*DIM+255)/256, 256, 0, stream>>>(w1a, Wt1a, F0, DIM, mode);
    transpose_cvt<<<(DIM*DIM+255)/256, 256, 0, stream>>>(w1b, Wt1b, DIM, DIM, mode);
    transpose_cvt<<<(DIM*DIM+255)/256, 256, 0, stream>>>(w2a, Wt2a, DIM, DIM, mode);
    transpose_cvt<<<(DIM*DIM+255)/256, 256, 0, stream>>>(w2b, Wt2b, DIM, DIM, mode);
    transpose_cvt<<<(DIM*DIM+255)/256, 256, 0, stream>>>(w3a, Wt3a, DIM, DIM, mode);
    transpose_cvt<<<(DIM*DIM+255)/256, 256, 0, stream>>>(w3b, Wt3b, DIM, DIM, mode);
    cvt_wfc<<<(DIM*NC)/256, 256, 0, stream>>>(wfc, Wfc, mode);
    cvt_vecs<<<11, 256, 0, stream>>>(b1a,b1b,g1,be1,b2a,b2b,g2,be2,b3a,b3b,bfc, Vc, mode);

    dim3 ggrid(MPAD/TBM, DIM/TBN);   // (782, 2)

    // ---- layer 1 ----
    agg_kernel<2><<<NND/4, 256, 0, stream>>>((const u16*)x, Xc, mode, rp, ssrc, Q,
                                             stats, Vc, Vc, 0, NND);
    gemm128<<<ggrid, 256, 0, stream>>>(Q, Wt1a, Vc+0*256, P, DIM, F0, 1);
    gemm128<<<ggrid, 256, 0, stream>>>(P, Wt1b, Vc+1*256, Q, DIM, DIM, 1);
    hipMemsetAsync(stats, 0, 2*DIM*4, stream);
    bn_stats<<<(NND+511)/512, 256, 0, stream>>>(Q, stats, NND);

    // ---- layer 2 (agg applies BN1 affine on the fly) ----
    agg_kernel<4><<<NND/4, 256, 0, stream>>>(Q, Q, mode, rp, ssrc, P,
                                             stats, Vc+2*256, Vc+3*256, 1, NND);
    gemm128<<<ggrid, 256, 0, stream>>>(P, Wt2a, Vc+4*256, Q, DIM, DIM, 1);
    gemm128<<<ggrid, 256, 0, stream>>>(Q, Wt2b, Vc+5*256, P, DIM, DIM, 1);
    hipMemsetAsync(stats, 0, 2*DIM*4, stream);
    bn_stats<<<(NND+511)/512, 256, 0, stream>>>(P, stats, NND);

    // ---- layer 3 (agg applies BN2 affine on the fly) ----
    agg_kernel<4><<<NND/4, 256, 0, stream>>>(P, P, mode, rp, ssrc, Q,
                                             stats, Vc+6*256, Vc+7*256, 1, NND);
    gemm128<<<ggrid, 256, 0, stream>>>(Q, Wt3a, Vc+8*256, P, DIM, DIM, 1);
    gemm128<<<ggrid, 256, 0, stream>>>(P, Wt3b, Vc+9*256, Q, DIM, DIM, 1);

    // ---- FC + log_softmax ----
    fc_lsm<<<NND/16, 256, 0, stream>>>(Q, Wfc, Vc+10*256, d_out, mode, NND);
}

// Round 4
// 1178.102 us; speedup vs baseline: 1.9052x; 1.6226x over previous
//
#include <hip/hip_runtime.h>

typedef unsigned int  u32;
typedef unsigned short u16;

#define NND 100000
#define MPAD 100096   // 782*128, so the 128-row GEMM tiles need no M guards
#define NE  3200000
#define F0  128
#define DIM 256
#define NC  16

// CSR bucketing
#define BSH   9                   // 512 nodes per bucket
#define NBUCK 196                 // ceil(100096/512)
#define CAP   18432               // max edges/bucket (mean 16384, sigma ~128)
#define EPB   8192                // edges per Phase-A block

typedef __bf16 bf16x8 __attribute__((ext_vector_type(8)));
typedef float  f32x4  __attribute__((ext_vector_type(4)));

__device__ __forceinline__ float b2f(u16 h){ return __uint_as_float(((u32)h)<<16); }
__device__ __forceinline__ u16 f2b(float f){
    u32 u = __float_as_uint(f);
    return (u16)((u + 0x7fffu + ((u>>16)&1u)) >> 16);
}
__device__ __forceinline__ float lo16(u32 u){ return __uint_as_float(u<<16); }
__device__ __forceinline__ float hi16(u32 u){ return __uint_as_float(u & 0xffff0000u); }

__device__ __forceinline__ void gload16(const u16* g, u16* l){
    __builtin_amdgcn_global_load_lds(
        (const __attribute__((address_space(1))) u32*)g,
        (__attribute__((address_space(3))) u32*)l, 16, 0, 0);
}

// ---------------- dtype probe ----------------
// mode[0]=1 if floats are f32 (else bf16); mode[1]=1 if edge_index is int64 (else int32)
__global__ void probe_kernel(const u32* __restrict__ xw, const int* __restrict__ ei,
                             int* __restrict__ mode){
    if(threadIdx.x==0 && blockIdx.x==0){
        int insane = 0;
        for(int i=0;i<64;i++){
            u32 w  = xw[i];
            u32 lo = w & 0xffffu;
            u32 e  = (lo >> 7) & 0xff;
            if(lo != 0 && (e < 48 || e > 208)) insane++;
        }
        mode[0] = (insane > 8) ? 1 : 0;
        int zeros = 0;
        for(int i=0;i<16;i++) if(ei[2*i+1]==0) zeros++;
        mode[1] = (zeros==16) ? 1 : 0;
    }
}

__device__ __forceinline__ int ld_src(const int* ei, int i64f, long e){
    return i64f ? ei[2*e] : ei[e];
}
__device__ __forceinline__ int ld_dst(const int* ei, int i64f, long e){
    return i64f ? ei[2*((long)NE + e)] : ei[(long)NE + e];
}

// ---------------- CSR build, Phase A: bucket scatter (counting-sort per block) ------
// packs (src<<9 | dst_local) into u32 per edge, grouped by bucket into bucketArr.
__global__ __launch_bounds__(256) void bucketA(const int* __restrict__ ei,
        const int* __restrict__ mode, u32* __restrict__ bucketArr,
        int* __restrict__ gcur){
    __shared__ u32 stag[EPB];        // 32 KB
    __shared__ u16 sbuck[EPB];       // 16 KB
    __shared__ int cnt[NBUCK];
    __shared__ int ofs[NBUCK];
    __shared__ int wofs[NBUCK];
    __shared__ int gbase[NBUCK];
    __shared__ int ps[256];
    int tid = threadIdx.x;
    int i64f = mode[1];
    long e0 = (long)blockIdx.x * EPB;
    int n = (int)min((long)EPB, (long)NE - e0);
    if(tid < NBUCK) cnt[tid] = 0;
    __syncthreads();
    for(int i=tid;i<n;i+=256){
        int d = ld_dst(ei, i64f, e0+i);
        atomicAdd(&cnt[d>>BSH], 1);
    }
    __syncthreads();
    // exclusive scan of cnt -> ofs (Hillis-Steele over 256 slots)
    ps[tid] = (tid < NBUCK) ? cnt[tid] : 0;
    __syncthreads();
    for(int o=1;o<256;o<<=1){
        int v = (tid>=o) ? ps[tid-o] : 0;
        __syncthreads();
        ps[tid] += v;
        __syncthreads();
    }
    if(tid < NBUCK){
        int ex = ps[tid] - cnt[tid];
        ofs[tid] = ex; wofs[tid] = ex;
        gbase[tid] = cnt[tid] ? atomicAdd(&gcur[tid], cnt[tid]) : 0;
    }
    __syncthreads();
    // place into LDS staging grouped by bucket
    for(int i=tid;i<n;i+=256){
        int s = ld_src(ei, i64f, e0+i);
        int d = ld_dst(ei, i64f, e0+i);
        int b = d>>BSH;
        int r = atomicAdd(&wofs[b], 1);
        stag[r]  = ((u32)s<<BSH) | (u32)(d & ((1<<BSH)-1));
        sbuck[r] = (u16)b;
    }
    __syncthreads();
    // stream out: per-bucket runs -> mostly full-line writes
    for(int i=tid;i<n;i+=256){
        int b = sbuck[i];
        int pos = gbase[b] + (i - ofs[b]);
        if(pos < CAP) bucketArr[(size_t)b*CAP + pos] = stag[i];
    }
}

// exclusive scan of 196 bucket counts -> bbase
__global__ void scan_buckets(const int* __restrict__ gcur, int* __restrict__ bbase){
    __shared__ int ps[256];
    int t = threadIdx.x;
    int c = (t < NBUCK) ? gcur[t] : 0;
    ps[t] = c;
    __syncthreads();
    for(int o=1;o<256;o<<=1){
        int v = (t>=o) ? ps[t-o] : 0;
        __syncthreads();
        ps[t] += v;
        __syncthreads();
    }
    if(t < NBUCK) bbase[t] = ps[t] - c;
}

// ---------------- CSR build, Phase B: per-bucket rp + coalesced ssrc ---------------
__global__ __launch_bounds__(256) void bucketB(const u32* __restrict__ bucketArr,
        const int* __restrict__ gcnt, const int* __restrict__ bbase,
        int* __restrict__ rp, int* __restrict__ ssrc){
    __shared__ u32 stag[CAP];        // 72 KB
    __shared__ int deg[512];
    __shared__ int lrp[512];
    __shared__ int cur[512];
    __shared__ int ps[256];
    int b = blockIdx.x, tid = threadIdx.x;
    int n = min(gcnt[b], CAP);
    int base = bbase[b];
    const u32* ba = bucketArr + (size_t)b*CAP;
    deg[tid] = 0; deg[tid+256] = 0;
    __syncthreads();
    for(int i=tid;i<n;i+=256){
        atomicAdd(&deg[ba[i] & 511], 1);
    }
    __syncthreads();
    // exclusive scan of deg[512] with 256 threads: pair-sum then HS
    ps[tid] = deg[2*tid] + deg[2*tid+1];
    __syncthreads();
    for(int o=1;o<256;o<<=1){
        int v = (tid>=o) ? ps[tid-o] : 0;
        __syncthreads();
        ps[tid] += v;
        __syncthreads();
    }
    {
        int ep = (tid==0) ? 0 : ps[tid-1];
        lrp[2*tid]   = ep;
        lrp[2*tid+1] = ep + deg[2*tid];
        cur[2*tid]   = lrp[2*tid];
        cur[2*tid+1] = lrp[2*tid+1];
    }
    __syncthreads();
    // write global rp for this bucket's nodes
    for(int i=tid;i<512;i+=256){
        int node = (b<<BSH) + i;
        if(node <= NND) rp[node] = base + lrp[i];
    }
    // rank edges into LDS staging
    for(int i=tid;i<n;i+=256){
        u32 v = ba[i];
        int r = atomicAdd(&cur[v & 511], 1);
        stag[r] = v >> BSH;   // src
    }
    __syncthreads();
    // coalesced stream-out
    for(int i=tid;i<n;i+=256){
        ssrc[base + i] = (int)stag[i];
    }
}

// ---------------- canonicalization (everything -> bf16) ----------------
__global__ void cvt_x(const float* __restrict__ xf, u16* __restrict__ Xc,
                      const int* __restrict__ mode){
    if(!mode[0]) return;
    size_t i = ((size_t)blockIdx.x*256 + threadIdx.x)*8;
    float4 a = *(const float4*)(xf+i);
    float4 b = *(const float4*)(xf+i+4);
    uint4 pk;
    pk.x = (u32)f2b(a.x) | ((u32)f2b(a.y)<<16);
    pk.y = (u32)f2b(a.z) | ((u32)f2b(a.w)<<16);
    pk.z = (u32)f2b(b.x) | ((u32)f2b(b.y)<<16);
    pk.w = (u32)f2b(b.z) | ((u32)f2b(b.w)<<16);
    *(uint4*)(Xc + i) = pk;
}

// W: KxN (f32 or bf16) -> Wt: NxK bf16
__global__ void transpose_cvt(const void* __restrict__ W, u16* __restrict__ Wt,
                              int K, int N, const int* __restrict__ mode){
    int id = blockIdx.x*256 + threadIdx.x;
    if(id < K*N){
        int k = id / N, n = id % N;
        float v = mode[0] ? ((const float*)W)[id] : b2f(((const u16*)W)[id]);
        Wt[n*K + k] = f2b(v);
    }
}

// wfc: (DIM x NC) -> WfcT: (NC x DIM) bf16
__global__ void cvt_wfc(const void* __restrict__ W, u16* __restrict__ Wc,
                        const int* __restrict__ mode){
    int id = blockIdx.x*256 + threadIdx.x;   // < DIM*NC = 4096
    int k = id / NC, c = id % NC;
    float v = mode[0] ? ((const float*)W)[id] : b2f(((const u16*)W)[id]);
    Wc[c*DIM + k] = f2b(v);
}

// 11 small vectors -> Vc (each at slot*256)
__global__ void cvt_vecs(const void* p0, const void* p1, const void* p2, const void* p3,
                         const void* p4, const void* p5, const void* p6, const void* p7,
                         const void* p8, const void* p9, const void* p10,
                         u16* __restrict__ Vc, const int* __restrict__ mode){
    const void* ps[11] = {p0,p1,p2,p3,p4,p5,p6,p7,p8,p9,p10};
    int lens[11] = {DIM,DIM,DIM,DIM,DIM,DIM,DIM,DIM,DIM,DIM,NC};
    int b = blockIdx.x, t = threadIdx.x;
    if(t < lens[b]){
        float v = mode[0] ? ((const float*)ps[b])[t] : b2f(((const u16*)ps[b])[t]);
        Vc[b*256 + t] = f2b(v);
    }
}

// ---------------- aggregation (+ fused BN affine of the PREVIOUS layer) ----------------
// out[i] = affine( h[i] + sum_{e in row i} h[src[e]] )
template<int VEC>
__global__ __launch_bounds__(256) void agg_kernel(const u16* __restrict__ hA,
        const u16* __restrict__ hB, const int* __restrict__ mode,
        const int* __restrict__ rp, const int* __restrict__ ssrc,
        u16* __restrict__ out,
        const float* __restrict__ stats, const u16* __restrict__ g,
        const u16* __restrict__ be, int use_bn, int M){
    const int F = 64*VEC;
    int node = blockIdx.x*4 + (threadIdx.x>>6);
    if(node >= M) return;
    int lane = threadIdx.x & 63;
    int lv = lane*VEC;
    const u16* h = (VEC==2 && mode[0]) ? hB : hA;

    float acc[VEC];
    {   // self row
        const u16* bp = h + (size_t)node*F + lv;
        if(VEC==4){
            uint2 u = *(const uint2*)bp;
            acc[0]=lo16(u.x); acc[1]=hi16(u.x); acc[2]=lo16(u.y); acc[3]=hi16(u.y);
        } else {
            u32 u = *(const u32*)bp;
            acc[0]=lo16(u); acc[1]=hi16(u);
        }
    }

    auto gather4 = [&](int s0,int s1,int s2,int s3){
        const u16* p0 = h + (size_t)s0*F + lv;
        const u16* p1 = h + (size_t)s1*F + lv;
        const u16* p2 = h + (size_t)s2*F + lv;
        const u16* p3 = h + (size_t)s3*F + lv;
        if(VEC==4){
            uint2 u0=*(const uint2*)p0, u1=*(const uint2*)p1,
                  u2=*(const uint2*)p2, u3=*(const uint2*)p3;
            acc[0]+=lo16(u0.x)+lo16(u1.x)+lo16(u2.x)+lo16(u3.x);
            acc[1]+=hi16(u0.x)+hi16(u1.x)+hi16(u2.x)+hi16(u3.x);
            acc[2]+=lo16(u0.y)+lo16(u1.y)+lo16(u2.y)+lo16(u3.y);
            acc[3]+=hi16(u0.y)+hi16(u1.y)+hi16(u2.y)+hi16(u3.y);
        } else {
            u32 u0=*(const u32*)p0, u1=*(const u32*)p1,
                u2=*(const u32*)p2, u3=*(const u32*)p3;
            acc[0]+=lo16(u0)+lo16(u1)+lo16(u2)+lo16(u3);
            acc[1]+=hi16(u0)+hi16(u1)+hi16(u2)+hi16(u3);
        }
    };

    int e0 = rp[node], e1 = rp[node+1];
    int e = e0;
    int eend = e0 + ((e1-e0) & ~3);
    if(e < eend){
        int s0=ssrc[e+0], s1=ssrc[e+1], s2=ssrc[e+2], s3=ssrc[e+3];
        e += 4;
        for(; e < eend; e += 4){
            int t0=ssrc[e+0], t1=ssrc[e+1], t2=ssrc[e+2], t3=ssrc[e+3];
            gather4(s0,s1,s2,s3);
            s0=t0; s1=t1; s2=t2; s3=t3;
        }
        gather4(s0,s1,s2,s3);
    }
    for(; e<e1; e++){
        int s = ssrc[e];
        const u16* sp = h + (size_t)s*F + lv;
        if(VEC==4){
            uint2 u = *(const uint2*)sp;
            acc[0]+=lo16(u.x); acc[1]+=hi16(u.x); acc[2]+=lo16(u.y); acc[3]+=hi16(u.y);
        } else {
            u32 u = *(const u32*)sp;
            acc[0]+=lo16(u); acc[1]+=hi16(u);
        }
    }

    float aff_a[VEC], aff_b[VEC];
    if(use_bn){
        float inv_m = 1.0f / (float)M;
        #pragma unroll
        for(int v=0; v<VEC; v++){
            int f = lv + v;
            float mean = stats[f]*inv_m;
            float var  = fmaxf(stats[F+f]*inv_m - mean*mean, 0.f);
            float rstd = rsqrtf(var + 1e-5f);
            float gg = b2f(g[f]);
            aff_a[v] = gg*rstd;
            aff_b[v] = b2f(be[f]) - gg*rstd*mean;
        }
    } else {
        #pragma unroll
        for(int v=0; v<VEC; v++){ aff_a[v]=1.f; aff_b[v]=0.f; }
    }
    float cnt = (float)(e1-e0+1);

    u16* op = out + (size_t)node*F + lv;
    if(VEC==4){
        uint2 o;
        float r0 = aff_a[0]*acc[0] + cnt*aff_b[0];
        float r1 = aff_a[1]*acc[1] + cnt*aff_b[1];
        float r2 = aff_a[2]*acc[2] + cnt*aff_b[2];
        float r3 = aff_a[3]*acc[3] + cnt*aff_b[3];
        o.x = (u32)f2b(r0) | ((u32)f2b(r1)<<16);
        o.y = (u32)f2b(r2) | ((u32)f2b(r3)<<16);
        *(uint2*)op = o;
    } else {
        float r0 = aff_a[0]*acc[0] + cnt*aff_b[0];
        float r1 = aff_a[1]*acc[1] + cnt*aff_b[1];
        *(u32*)op = (u32)f2b(r0) | ((u32)f2b(r1)<<16);
    }
}

// ---------------- MFMA GEMM, 128x128 tile + optional fused BN-stats epilogue -------
#define TBM 128
#define TBN 128
#define TBK 32
__global__ __launch_bounds__(256) void gemm128(
        const u16* __restrict__ A, const u16* __restrict__ Bt,
        const u16* __restrict__ bias, u16* __restrict__ C,
        int N, int K, int do_relu, float* __restrict__ stats, int do_stats){
    __shared__ __align__(16) u16 lA[TBM*TBK];
    __shared__ __align__(16) u16 lB[TBN*TBK];
    __shared__ float colS[TBN], colS2[TBN];
    int tid = threadIdx.x;
    int w = tid>>6, lane = tid&63;
    int q = lane>>4, mr = lane&15;
    int wr = w>>1, wc = w&1;
    int m0 = blockIdx.x*TBM, n0 = blockIdx.y*TBN;

    if(do_stats){
        if(tid < TBN){ colS[tid]=0.f; colS2[tid]=0.f; }
    }

    f32x4 acc[4][4];
    #pragma unroll
    for(int i=0;i<4;i++)
        #pragma unroll
        for(int c=0;c<4;c++) acc[i][c] = (f32x4){0.f,0.f,0.f,0.f};

    const u16* ga0 = A  + (size_t)(m0 + w*32 + (lane>>2))*K + (lane&3)*8;
    const u16* ga1 = ga0 + (size_t)16*K;
    const u16* gb0 = Bt + (size_t)(n0 + w*32 + (lane>>2))*K + (lane&3)*8;
    const u16* gb1 = gb0 + (size_t)16*K;
    u16* la0 = &lA[(w*32)*TBK];    u16* la1 = la0 + 16*TBK;
    u16* lb0 = &lB[(w*32)*TBK];    u16* lb1 = lb0 + 16*TBK;

    for(int k0=0; k0<K; k0+=TBK){
        gload16(ga0, la0); gload16(ga1, la1);
        gload16(gb0, lb0); gload16(gb1, lb1);
        ga0 += TBK; ga1 += TBK; gb0 += TBK; gb1 += TBK;
        __syncthreads();
        bf16x8 af[4], bfr[4];
        #pragma unroll
        for(int i=0;i<4;i++)
            af[i] = *reinterpret_cast<const bf16x8*>(&lA[(wr*64 + i*16 + mr)*TBK + q*8]);
        #pragma unroll
        for(int c=0;c<4;c++)
            bfr[c] = *reinterpret_cast<const bf16x8*>(&lB[(wc*64 + c*16 + mr)*TBK + q*8]);
        #pragma unroll
        for(int i=0;i<4;i++)
            #pragma unroll
            for(int c=0;c<4;c++)
                acc[i][c] = __builtin_amdgcn_mfma_f32_16x16x32_bf16(af[i], bfr[c], acc[i][c], 0, 0, 0);
        __syncthreads();
    }

    #pragma unroll
    for(int c=0;c<4;c++){
        int lcol = wc*64 + c*16 + mr;
        int col  = n0 + lcol;
        float bv = b2f(bias[col]);
        float s = 0.f, s2 = 0.f;
        #pragma unroll
        for(int i=0;i<4;i++){
            int row = m0 + wr*64 + i*16 + q*4;
            #pragma unroll
            for(int r=0;r<4;r++){
                float v = acc[i][c][r] + bv;
                if(do_relu) v = fmaxf(v, 0.f);
                u16 o = f2b(v);
                C[(size_t)(row + r)*N + col] = o;
                if(do_stats && (row + r) < NND){
                    float vr = b2f(o);
                    s += vr; s2 += vr*vr;
                }
            }
        }
        if(do_stats){
            atomicAdd(&colS[lcol], s);
            atomicAdd(&colS2[lcol], s2);
        }
    }
    if(do_stats){
        __syncthreads();
        if(tid < TBN){
            int col = n0 + tid;
            atomicAdd(&stats[col], colS[tid]);
            atomicAdd(&stats[DIM+col], colS2[tid]);
        }
    }
}

// ---------------- FC (256->16) + log_softmax; wfc pre-transposed (NC x DIM) -------
__global__ __launch_bounds__(256) void fc_lsm(const u16* __restrict__ h,
        const u16* __restrict__ wfcT, const u16* __restrict__ bfc,
        void* __restrict__ out, const int* __restrict__ mode, int M){
    __shared__ float lds[256];
    __shared__ float rmx[16], rls[16];
    int tid = threadIdx.x;
    int r = tid>>4, c = tid&15;
    int row = blockIdx.x*16 + r;
    float acc = b2f(bfc[c]);
    const u16* hp = h + (size_t)row*DIM;
    const u16* wp = wfcT + c*DIM;
    for(int k=0;k<DIM;k+=8){
        uint4 hv = *(const uint4*)(hp+k);
        uint4 wv = *(const uint4*)(wp+k);
        acc += lo16(hv.x)*lo16(wv.x) + hi16(hv.x)*hi16(wv.x)
             + lo16(hv.y)*lo16(wv.y) + hi16(hv.y)*hi16(wv.y)
             + lo16(hv.z)*lo16(wv.z) + hi16(hv.z)*hi16(wv.z)
             + lo16(hv.w)*lo16(wv.w) + hi16(hv.w)*hi16(wv.w);
    }
    lds[tid] = acc;
    __syncthreads();
    if(c==0){
        float mx = -1e30f;
        for(int i=0;i<NC;i++) mx = fmaxf(mx, lds[r*NC+i]);
        float s = 0.f;
        for(int i=0;i<NC;i++) s += expf(lds[r*NC+i] - mx);
        rmx[r] = mx; rls[r] = logf(s);
    }
    __syncthreads();
    if(row < M){
        float v = acc - rmx[r] - rls[r];
        if(mode[0]) ((float*)out)[(size_t)row*NC + c] = v;
        else        ((u16*)out)[(size_t)row*NC + c] = f2b(v);
    }
}

extern "C" void kernel_launch(void* const* d_in, const int* in_sizes, int n_in,
                              void* d_out, int out_size, void* d_ws, size_t ws_size,
                              hipStream_t stream){
    const void* x   = d_in[0];
    const int*  ei  = (const int*)d_in[1];
    const void* w1a = d_in[2];  const void* b1a = d_in[3];
    const void* w1b = d_in[4];  const void* b1b = d_in[5];
    const void* g1  = d_in[6];  const void* be1 = d_in[7];
    const void* w2a = d_in[8];  const void* b2a = d_in[9];
    const void* w2b = d_in[10]; const void* b2b = d_in[11];
    const void* g2  = d_in[12]; const void* be2 = d_in[13];
    const void* w3a = d_in[14]; const void* b3a = d_in[15];
    const void* w3b = d_in[16]; const void* b3b = d_in[17];
    const void* wfc = d_in[18]; const void* bfc = d_in[19];

    char* base = (char*)d_ws;
    size_t off = 0;
    auto alloc = [&](size_t bytes)->void*{
        void* p = base + off;
        off = (off + bytes + 255) & ~(size_t)255;
        return p;
    };
    u16*  P     = (u16*)alloc((size_t)MPAD*DIM*2);   // also aliases Xc
    u16*  Q     = (u16*)alloc((size_t)MPAD*DIM*2);
    int*  ssrc  = (int*)alloc((size_t)NE*4);
    u32*  bArr  = (u32*)alloc((size_t)NBUCK*CAP*4);
    int*  gcur  = (int*)alloc((size_t)NBUCK*4);
    int*  bbase = (int*)alloc((size_t)NBUCK*4);
    int*  rp    = (int*)alloc((size_t)(NND+1)*4);
    float* stats= (float*)alloc(2*DIM*4);
    int*  mode  = (int*)alloc(16);
    u16* Wt1a = (u16*)alloc((size_t)F0*DIM*2);
    u16* Wt1b = (u16*)alloc((size_t)DIM*DIM*2);
    u16* Wt2a = (u16*)alloc((size_t)DIM*DIM*2);
    u16* Wt2b = (u16*)alloc((size_t)DIM*DIM*2);
    u16* Wt3a = (u16*)alloc((size_t)DIM*DIM*2);
    u16* Wt3b = (u16*)alloc((size_t)DIM*DIM*2);
    u16* Vc   = (u16*)alloc(11*256*2);
    u16* Wfc  = (u16*)alloc((size_t)DIM*NC*2);
    u16* Xc   = P;  // consumed by layer-1 agg before P is first written

    probe_kernel<<<1, 64, 0, stream>>>((const u32*)x, ei, mode);

    // CSR build: bucket scatter -> bucket scan -> per-bucket rp/ssrc
    hipMemsetAsync(gcur, 0, (size_t)NBUCK*4, stream);
    bucketA<<<(NE + EPB - 1)/EPB, 256, 0, stream>>>(ei, mode, bArr, gcur);
    scan_buckets<<<1, 256, 0, stream>>>(gcur, bbase);
    bucketB<<<NBUCK, 256, 0, stream>>>(bArr, gcur, bbase, rp, ssrc);

    // canonicalize params (and x if f32)
    cvt_x<<<(NND*F0)/(256*8), 256, 0, stream>>>((const float*)x, Xc, mode);
    transpose_cvt<<<(F0*DIM+255)/256, 256, 0, stream>>>(w1a, Wt1a, F0, DIM, mode);
    transpose_cvt<<<(DIM*DIM+255)/256, 256, 0, stream>>>(w1b, Wt1b, DIM, DIM, mode);
    transpose_cvt<<<(DIM*DIM+255)/256, 256, 0, stream>>>(w2a, Wt2a, DIM, DIM, mode);
    transpose_cvt<<<(DIM*DIM+255)/256, 256, 0, stream>>>(w2b, Wt2b, DIM, DIM, mode);
    transpose_cvt<<<(DIM*DIM+255)/256, 256, 0, stream>>>(w3a, Wt3a, DIM, DIM, mode);
    transpose_cvt<<<(DIM*DIM+255)/256, 256, 0, stream>>>(w3b, Wt3b, DIM, DIM, mode);
    cvt_wfc<<<(DIM*NC)/256, 256, 0, stream>>>(wfc, Wfc, mode);
    cvt_vecs<<<11, 256, 0, stream>>>(b1a,b1b,g1,be1,b2a,b2b,g2,be2,b3a,b3b,bfc, Vc, mode);

    dim3 ggrid(MPAD/TBM, DIM/TBN);   // (782, 2)

    // ---- layer 1 ----
    hipMemsetAsync(stats, 0, 2*DIM*4, stream);
    agg_kernel<2><<<NND/4, 256, 0, stream>>>((const u16*)x, Xc, mode, rp, ssrc, Q,
                                             stats, Vc, Vc, 0, NND);
    gemm128<<<ggrid, 256, 0, stream>>>(Q, Wt1a, Vc+0*256, P, DIM, F0, 1, stats, 0);
    gemm128<<<ggrid, 256, 0, stream>>>(P, Wt1b, Vc+1*256, Q, DIM, DIM, 1, stats, 1);

    // ---- layer 2 (agg applies BN1 affine on the fly) ----
    agg_kernel<4><<<NND/4, 256, 0, stream>>>(Q, Q, mode, rp, ssrc, P,
                                             stats, Vc+2*256, Vc+3*256, 1, NND);
    hipMemsetAsync(stats, 0, 2*DIM*4, stream);   // safe: agg consumed stats already
    gemm128<<<ggrid, 256, 0, stream>>>(P, Wt2a, Vc+4*256, Q, DIM, DIM, 1, stats, 0);
    gemm128<<<ggrid, 256, 0, stream>>>(Q, Wt2b, Vc+5*256, P, DIM, DIM, 1, stats, 1);

    // ---- layer 3 (agg applies BN2 affine on the fly) ----
    agg_kernel<4><<<NND/4, 256, 0, stream>>>(P, P, mode, rp, ssrc, Q,
                                             stats, Vc+6*256, Vc+7*256, 1, NND);
    gemm128<<<ggrid, 256, 0, stream>>>(Q, Wt3a, Vc+8*256, P, DIM, DIM, 1, stats, 0);
    gemm128<<<ggrid, 256, 0, stream>>>(P, Wt3b, Vc+9*256, Q, DIM, DIM, 1, stats, 0);

    // ---- FC + log_softmax ----
    fc_lsm<<<NND/16, 256, 0, stream>>>(Q, Wfc, Vc+10*256, d_out, mode, NND);
}

// Round 5
// 1153.406 us; speedup vs baseline: 1.9460x; 1.0214x over previous
//
#include <hip/hip_runtime.h>

typedef unsigned int  u32;
typedef unsigned short u16;

#define NND 100000
#define MPAD 100096   // 782*128, so the 128-row GEMM tiles need no M guards
#define NE  3200000
#define F0  128
#define DIM 256
#define NC  16

// CSR bucketing
#define BSH   9                   // 512 nodes per bucket
#define NBUCK 196                 // ceil(100096/512)
#define CAP   18432               // max edges/bucket (mean 16384, sigma ~128)
#define EPB   8192                // edges per Phase-A block

typedef __bf16 bf16x8 __attribute__((ext_vector_type(8)));
typedef float  f32x4  __attribute__((ext_vector_type(4)));

__device__ __forceinline__ float b2f(u16 h){ return __uint_as_float(((u32)h)<<16); }
__device__ __forceinline__ u16 f2b(float f){
    u32 u = __float_as_uint(f);
    return (u16)((u + 0x7fffu + ((u>>16)&1u)) >> 16);
}
__device__ __forceinline__ float lo16(u32 u){ return __uint_as_float(u<<16); }
__device__ __forceinline__ float hi16(u32 u){ return __uint_as_float(u & 0xffff0000u); }

__device__ __forceinline__ void gload16(const u16* g, u16* l){
    __builtin_amdgcn_global_load_lds(
        (const __attribute__((address_space(1))) u32*)g,
        (__attribute__((address_space(3))) u32*)l, 16, 0, 0);
}

// ---------------- probe + zero-init (gcur, statsA, statsB) ----------------
// mode[0]=1 if floats are f32 (else bf16); mode[1]=1 if edge_index is int64 (else int32)
__global__ void probe_kernel(const u32* __restrict__ xw, const int* __restrict__ ei,
                             int* __restrict__ mode, int* __restrict__ gcur,
                             float* __restrict__ stats){
    int t = threadIdx.x;
    if(t < NBUCK) gcur[t] = 0;
    #pragma unroll
    for(int i=0;i<4;i++) stats[t + 256*i] = 0.f;   // 4*DIM floats (statsA+statsB)
    if(t==0){
        int insane = 0;
        for(int i=0;i<64;i++){
            u32 w  = xw[i];
            u32 lo = w & 0xffffu;
            u32 e  = (lo >> 7) & 0xff;
            if(lo != 0 && (e < 48 || e > 208)) insane++;
        }
        mode[0] = (insane > 8) ? 1 : 0;
        int zeros = 0;
        for(int i=0;i<16;i++) if(ei[2*i+1]==0) zeros++;
        mode[1] = (zeros==16) ? 1 : 0;
    }
}

__device__ __forceinline__ int ld_src(const int* ei, int i64f, long e){
    return i64f ? ei[2*e] : ei[e];
}
__device__ __forceinline__ int ld_dst(const int* ei, int i64f, long e){
    return i64f ? ei[2*((long)NE + e)] : ei[(long)NE + e];
}

// ---------------- CSR build, Phase A: bucket scatter (counting-sort per block) ------
__global__ __launch_bounds__(256) void bucketA(const int* __restrict__ ei,
        const int* __restrict__ mode, u32* __restrict__ bucketArr,
        int* __restrict__ gcur){
    __shared__ u32 stag[EPB];        // 32 KB
    __shared__ u16 sbuck[EPB];       // 16 KB
    __shared__ int cnt[NBUCK];
    __shared__ int ofs[NBUCK];
    __shared__ int wofs[NBUCK];
    __shared__ int gbase[NBUCK];
    __shared__ int ps[256];
    int tid = threadIdx.x;
    int i64f = mode[1];
    long e0 = (long)blockIdx.x * EPB;
    int n = (int)min((long)EPB, (long)NE - e0);
    if(tid < NBUCK) cnt[tid] = 0;
    __syncthreads();
    for(int i=tid;i<n;i+=256){
        int d = ld_dst(ei, i64f, e0+i);
        atomicAdd(&cnt[d>>BSH], 1);
    }
    __syncthreads();
    ps[tid] = (tid < NBUCK) ? cnt[tid] : 0;
    __syncthreads();
    for(int o=1;o<256;o<<=1){
        int v = (tid>=o) ? ps[tid-o] : 0;
        __syncthreads();
        ps[tid] += v;
        __syncthreads();
    }
    if(tid < NBUCK){
        int ex = ps[tid] - cnt[tid];
        ofs[tid] = ex; wofs[tid] = ex;
        gbase[tid] = cnt[tid] ? atomicAdd(&gcur[tid], cnt[tid]) : 0;
    }
    __syncthreads();
    for(int i=tid;i<n;i+=256){
        int s = ld_src(ei, i64f, e0+i);
        int d = ld_dst(ei, i64f, e0+i);
        int b = d>>BSH;
        int r = atomicAdd(&wofs[b], 1);
        stag[r]  = ((u32)s<<BSH) | (u32)(d & ((1<<BSH)-1));
        sbuck[r] = (u16)b;
    }
    __syncthreads();
    for(int i=tid;i<n;i+=256){
        int b = sbuck[i];
        int pos = gbase[b] + (i - ofs[b]);
        if(pos < CAP) bucketArr[(size_t)b*CAP + pos] = stag[i];
    }
}

// ---------------- CSR build, Phase B: inline bucket-scan + per-bucket rp/ssrc -------
__global__ __launch_bounds__(256) void bucketB(const u32* __restrict__ bucketArr,
        const int* __restrict__ gcnt,
        int* __restrict__ rp, int* __restrict__ ssrc){
    __shared__ u32 stag[CAP];        // 72 KB
    __shared__ int deg[512];
    __shared__ int lrp[512];
    __shared__ int cur[512];
    __shared__ int ps[256];
    int b = blockIdx.x, tid = threadIdx.x;
    // inclusive scan of gcnt over 196 buckets -> base for this block
    ps[tid] = (tid < NBUCK) ? gcnt[tid] : 0;
    __syncthreads();
    for(int o=1;o<256;o<<=1){
        int v = (tid>=o) ? ps[tid-o] : 0;
        __syncthreads();
        ps[tid] += v;
        __syncthreads();
    }
    int base = (b>0) ? ps[b-1] : 0;
    int n = min(gcnt[b], CAP);
    const u32* ba = bucketArr + (size_t)b*CAP;
    deg[tid] = 0; deg[tid+256] = 0;
    __syncthreads();
    for(int i=tid;i<n;i+=256){
        atomicAdd(&deg[ba[i] & 511], 1);
    }
    __syncthreads();
    ps[tid] = deg[2*tid] + deg[2*tid+1];
    __syncthreads();
    for(int o=1;o<256;o<<=1){
        int v = (tid>=o) ? ps[tid-o] : 0;
        __syncthreads();
        ps[tid] += v;
        __syncthreads();
    }
    {
        int ep = (tid==0) ? 0 : ps[tid-1];
        lrp[2*tid]   = ep;
        lrp[2*tid+1] = ep + deg[2*tid];
        cur[2*tid]   = lrp[2*tid];
        cur[2*tid+1] = lrp[2*tid+1];
    }
    __syncthreads();
    for(int i=tid;i<512;i+=256){
        int node = (b<<BSH) + i;
        if(node <= NND) rp[node] = base + lrp[i];
    }
    for(int i=tid;i<n;i+=256){
        u32 v = ba[i];
        int r = atomicAdd(&cur[v & 511], 1);
        stag[r] = v >> BSH;   // src
    }
    __syncthreads();
    for(int i=tid;i<n;i+=256){
        ssrc[base + i] = (int)stag[i];
    }
}

// ---------------- x canonicalization (f32 -> bf16) ----------------
__global__ void cvt_x(const float* __restrict__ xf, u16* __restrict__ Xc,
                      const int* __restrict__ mode){
    if(!mode[0]) return;
    size_t i = ((size_t)blockIdx.x*256 + threadIdx.x)*8;
    float4 a = *(const float4*)(xf+i);
    float4 b = *(const float4*)(xf+i+4);
    uint4 pk;
    pk.x = (u32)f2b(a.x) | ((u32)f2b(a.y)<<16);
    pk.y = (u32)f2b(a.z) | ((u32)f2b(a.w)<<16);
    pk.z = (u32)f2b(b.x) | ((u32)f2b(b.y)<<16);
    pk.w = (u32)f2b(b.z) | ((u32)f2b(b.w)<<16);
    *(uint4*)(Xc + i) = pk;
}

// ---------------- merged weight/bias canonicalization (one launch) ----------------
__device__ __forceinline__ float ldf(const void* p, int i, int f32f){
    return f32f ? ((const float*)p)[i] : b2f(((const u16*)p)[i]);
}
__global__ void merged_cvt(
        const void* w1a, const void* w1b, const void* w2a, const void* w2b,
        const void* w3a, const void* w3b, const void* wfc,
        const void* b1a, const void* b1b, const void* g1, const void* be1,
        const void* b2a, const void* b2b, const void* g2, const void* be2,
        const void* b3a, const void* b3b, const void* bfcp,
        u16* __restrict__ Wt1a, u16* __restrict__ Wt1b, u16* __restrict__ Wt2a,
        u16* __restrict__ Wt2b, u16* __restrict__ Wt3a, u16* __restrict__ Wt3b,
        u16* __restrict__ Wfc, u16* __restrict__ Vc, const int* __restrict__ mode){
    int b = blockIdx.x, t = threadIdx.x;
    int f32f = mode[0];
    if(b < 128){                      // w1a: (F0 x DIM) -> (DIM x F0)
        int id = b*256 + t;
        int k = id / DIM, n = id % DIM;
        Wt1a[n*F0 + k] = f2b(ldf(w1a, id, f32f));
        return;
    }
    b -= 128;
    if(b < 5*256){                    // w1b,w2a,w2b,w3a,w3b: (DIM x DIM) -> T
        int wi = b >> 8;
        const void* W = (wi==0)?w1b:(wi==1)?w2a:(wi==2)?w2b:(wi==3)?w3a:w3b;
        u16* Wt = (wi==0)?Wt1b:(wi==1)?Wt2a:(wi==2)?Wt2b:(wi==3)?Wt3a:Wt3b;
        int id = (b & 255)*256 + t;
        int k = id / DIM, n = id % DIM;
        Wt[n*DIM + k] = f2b(ldf(W, id, f32f));
        return;
    }
    b -= 5*256;
    if(b < 16){                       // wfc: (DIM x NC) -> (NC x DIM)
        int id = b*256 + t;
        int k = id / NC, c = id % NC;
        Wfc[c*DIM + k] = f2b(ldf(wfc, id, f32f));
        return;
    }
    b -= 16;
    {                                 // 11 small vectors
        const void* ps[11] = {b1a,b1b,g1,be1,b2a,b2b,g2,be2,b3a,b3b,bfcp};
        int lens[11] = {DIM,DIM,DIM,DIM,DIM,DIM,DIM,DIM,DIM,DIM,NC};
        if(t < lens[b]) Vc[b*256 + t] = f2b(ldf(ps[b], t, f32f));
    }
}

// ---------------- aggregation v2: 16B lanes, multiple items per wave ----------------
// out[i] = affine( h[i] + sum_{e in row i} h[src[e]] ); items = {self} ∪ neighbors
// LPI = lanes per item (32 for F=256, 16 for F=128); IPW = 64/LPI items per wave.
template<int LPI>
__global__ __launch_bounds__(256) void agg2(const u16* __restrict__ hA,
        const u16* __restrict__ hB, const int* __restrict__ mode,
        const int* __restrict__ rp, const int* __restrict__ ssrc,
        u16* __restrict__ out,
        const float* __restrict__ stats, const u16* __restrict__ g,
        const u16* __restrict__ be, int use_bn, int M){
    const int F = LPI*8;
    const int IPW = 64/LPI;
    int node = blockIdx.x*4 + (threadIdx.x>>6);
    if(node >= M) return;
    int lane = threadIdx.x & 63;
    int li   = lane & (LPI-1);       // feature octet index
    int slot = lane / LPI;           // item slot within wave
    const u16* h = (LPI==16 && mode[0]) ? hB : hA;
    const int boff = li*8;

    int e0 = rp[node], e1 = rp[node+1];
    int n_items = e1 - e0 + 1;       // self + neighbors
    float acc[8] = {0.f,0.f,0.f,0.f,0.f,0.f,0.f,0.f};

    auto item = [&](int i)->int { return (i==0) ? node : ssrc[e0 + i - 1]; };
    auto addu = [&](uint4 u){
        acc[0]+=lo16(u.x); acc[1]+=hi16(u.x);
        acc[2]+=lo16(u.y); acc[3]+=hi16(u.y);
        acc[4]+=lo16(u.z); acc[5]+=hi16(u.z);
        acc[6]+=lo16(u.w); acc[7]+=hi16(u.w);
    };

    int i = 0;
    for(; i + 4*IPW <= n_items; i += 4*IPW){
        int s0 = item(i + slot);
        int s1 = item(i + IPW + slot);
        int s2 = item(i + 2*IPW + slot);
        int s3 = item(i + 3*IPW + slot);
        uint4 u0 = *(const uint4*)(h + (size_t)s0*F + boff);
        uint4 u1 = *(const uint4*)(h + (size_t)s1*F + boff);
        uint4 u2 = *(const uint4*)(h + (size_t)s2*F + boff);
        uint4 u3 = *(const uint4*)(h + (size_t)s3*F + boff);
        addu(u0); addu(u1); addu(u2); addu(u3);
    }
    for(; i + IPW <= n_items; i += IPW){
        int s = item(i + slot);
        addu(*(const uint4*)(h + (size_t)s*F + boff));
    }
    if(i < n_items){
        int r = n_items - i;         // 1..IPW-1
        if(slot < r){
            int s = item(i + slot);
            addu(*(const uint4*)(h + (size_t)s*F + boff));
        }
    }

    // combine partial sums across item slots
    #pragma unroll
    for(int j=0;j<8;j++){
        if(LPI==16) acc[j] += __shfl_xor(acc[j], 16);
        acc[j] += __shfl_xor(acc[j], 32);
    }

    if(slot == 0){
        float res[8];
        if(use_bn){
            float inv_m = 1.0f / (float)M;
            float cnt = (float)n_items;
            #pragma unroll
            for(int j=0;j<8;j++){
                int f = boff + j;
                float mean = stats[f]*inv_m;
                float var  = fmaxf(stats[F+f]*inv_m - mean*mean, 0.f);
                float rstd = rsqrtf(var + 1e-5f);
                float gg = b2f(g[f]);
                float a = gg*rstd;
                float bb = b2f(be[f]) - a*mean;
                res[j] = a*acc[j] + cnt*bb;
            }
        } else {
            #pragma unroll
            for(int j=0;j<8;j++) res[j] = acc[j];
        }
        uint4 o;
        o.x = (u32)f2b(res[0]) | ((u32)f2b(res[1])<<16);
        o.y = (u32)f2b(res[2]) | ((u32)f2b(res[3])<<16);
        o.z = (u32)f2b(res[4]) | ((u32)f2b(res[5])<<16);
        o.w = (u32)f2b(res[6]) | ((u32)f2b(res[7])<<16);
        *(uint4*)(out + (size_t)node*F + boff) = o;
    }
}

// ---------------- MFMA GEMM, 128x128 tile + optional fused BN-stats epilogue -------
#define TBM 128
#define TBN 128
#define TBK 32
__global__ __launch_bounds__(256) void gemm128(
        const u16* __restrict__ A, const u16* __restrict__ Bt,
        const u16* __restrict__ bias, u16* __restrict__ C,
        int N, int K, int do_relu, float* __restrict__ stats, int do_stats){
    __shared__ __align__(16) u16 lA[TBM*TBK];
    __shared__ __align__(16) u16 lB[TBN*TBK];
    __shared__ float colS[TBN], colS2[TBN];
    int tid = threadIdx.x;
    int w = tid>>6, lane = tid&63;
    int q = lane>>4, mr = lane&15;
    int wr = w>>1, wc = w&1;
    int m0 = blockIdx.x*TBM, n0 = blockIdx.y*TBN;

    if(do_stats){
        if(tid < TBN){ colS[tid]=0.f; colS2[tid]=0.f; }
    }

    f32x4 acc[4][4];
    #pragma unroll
    for(int i=0;i<4;i++)
        #pragma unroll
        for(int c=0;c<4;c++) acc[i][c] = (f32x4){0.f,0.f,0.f,0.f};

    const u16* ga0 = A  + (size_t)(m0 + w*32 + (lane>>2))*K + (lane&3)*8;
    const u16* ga1 = ga0 + (size_t)16*K;
    const u16* gb0 = Bt + (size_t)(n0 + w*32 + (lane>>2))*K + (lane&3)*8;
    const u16* gb1 = gb0 + (size_t)16*K;
    u16* la0 = &lA[(w*32)*TBK];    u16* la1 = la0 + 16*TBK;
    u16* lb0 = &lB[(w*32)*TBK];    u16* lb1 = lb0 + 16*TBK;

    for(int k0=0; k0<K; k0+=TBK){
        gload16(ga0, la0); gload16(ga1, la1);
        gload16(gb0, lb0); gload16(gb1, lb1);
        ga0 += TBK; ga1 += TBK; gb0 += TBK; gb1 += TBK;
        __syncthreads();
        bf16x8 af[4], bfr[4];
        #pragma unroll
        for(int i=0;i<4;i++)
            af[i] = *reinterpret_cast<const bf16x8*>(&lA[(wr*64 + i*16 + mr)*TBK + q*8]);
        #pragma unroll
        for(int c=0;c<4;c++)
            bfr[c] = *reinterpret_cast<const bf16x8*>(&lB[(wc*64 + c*16 + mr)*TBK + q*8]);
        #pragma unroll
        for(int i=0;i<4;i++)
            #pragma unroll
            for(int c=0;c<4;c++)
                acc[i][c] = __builtin_amdgcn_mfma_f32_16x16x32_bf16(af[i], bfr[c], acc[i][c], 0, 0, 0);
        __syncthreads();
    }

    #pragma unroll
    for(int c=0;c<4;c++){
        int lcol = wc*64 + c*16 + mr;
        int col  = n0 + lcol;
        float bv = b2f(bias[col]);
        float s = 0.f, s2 = 0.f;
        #pragma unroll
        for(int i=0;i<4;i++){
            int row = m0 + wr*64 + i*16 + q*4;
            #pragma unroll
            for(int r=0;r<4;r++){
                float v = acc[i][c][r] + bv;
                if(do_relu) v = fmaxf(v, 0.f);
                u16 o = f2b(v);
                C[(size_t)(row + r)*N + col] = o;
                if(do_stats && (row + r) < NND){
                    float vr = b2f(o);
                    s += vr; s2 += vr*vr;
                }
            }
        }
        if(do_stats){
            atomicAdd(&colS[lcol], s);
            atomicAdd(&colS2[lcol], s2);
        }
    }
    if(do_stats){
        __syncthreads();
        if(tid < TBN){
            int col = n0 + tid;
            atomicAdd(&stats[col], colS[tid]);
            atomicAdd(&stats[DIM+col], colS2[tid]);
        }
    }
}

// ---------------- FC (256->16) + log_softmax; wfc pre-transposed (NC x DIM) -------
__global__ __launch_bounds__(256) void fc_lsm(const u16* __restrict__ h,
        const u16* __restrict__ wfcT, const u16* __restrict__ bfc,
        void* __restrict__ out, const int* __restrict__ mode, int M){
    __shared__ float lds[256];
    __shared__ float rmx[16], rls[16];
    int tid = threadIdx.x;
    int r = tid>>4, c = tid&15;
    int row = blockIdx.x*16 + r;
    float acc = b2f(bfc[c]);
    const u16* hp = h + (size_t)row*DIM;
    const u16* wp = wfcT + c*DIM;
    for(int k=0;k<DIM;k+=8){
        uint4 hv = *(const uint4*)(hp+k);
        uint4 wv = *(const uint4*)(wp+k);
        acc += lo16(hv.x)*lo16(wv.x) + hi16(hv.x)*hi16(wv.x)
             + lo16(hv.y)*lo16(wv.y) + hi16(hv.y)*hi16(wv.y)
             + lo16(hv.z)*lo16(wv.z) + hi16(hv.z)*hi16(wv.z)
             + lo16(hv.w)*lo16(wv.w) + hi16(hv.w)*hi16(wv.w);
    }
    lds[tid] = acc;
    __syncthreads();
    if(c==0){
        float mx = -1e30f;
        for(int i=0;i<NC;i++) mx = fmaxf(mx, lds[r*NC+i]);
        float s = 0.f;
        for(int i=0;i<NC;i++) s += expf(lds[r*NC+i] - mx);
        rmx[r] = mx; rls[r] = logf(s);
    }
    __syncthreads();
    if(row < M){
        float v = acc - rmx[r] - rls[r];
        if(mode[0]) ((float*)out)[(size_t)row*NC + c] = v;
        else        ((u16*)out)[(size_t)row*NC + c] = f2b(v);
    }
}

extern "C" void kernel_launch(void* const* d_in, const int* in_sizes, int n_in,
                              void* d_out, int out_size, void* d_ws, size_t ws_size,
                              hipStream_t stream){
    const void* x   = d_in[0];
    const int*  ei  = (const int*)d_in[1];
    const void* w1a = d_in[2];  const void* b1a = d_in[3];
    const void* w1b = d_in[4];  const void* b1b = d_in[5];
    const void* g1  = d_in[6];  const void* be1 = d_in[7];
    const void* w2a = d_in[8];  const void* b2a = d_in[9];
    const void* w2b = d_in[10]; const void* b2b = d_in[11];
    const void* g2  = d_in[12]; const void* be2 = d_in[13];
    const void* w3a = d_in[14]; const void* b3a = d_in[15];
    const void* w3b = d_in[16]; const void* b3b = d_in[17];
    const void* wfc = d_in[18]; const void* bfc = d_in[19];

    char* base = (char*)d_ws;
    size_t off = 0;
    auto alloc = [&](size_t bytes)->void*{
        void* p = base + off;
        off = (off + bytes + 255) & ~(size_t)255;
        return p;
    };
    u16*  P     = (u16*)alloc((size_t)MPAD*DIM*2);   // also aliases Xc
    u16*  Q     = (u16*)alloc((size_t)MPAD*DIM*2);
    int*  ssrc  = (int*)alloc((size_t)NE*4);
    u32*  bArr  = (u32*)alloc((size_t)NBUCK*CAP*4);
    int*  gcur  = (int*)alloc((size_t)NBUCK*4);
    int*  rp    = (int*)alloc((size_t)(NND+1)*4);
    float* stats= (float*)alloc(4*DIM*4);            // statsA | statsB
    int*  mode  = (int*)alloc(16);
    u16* Wt1a = (u16*)alloc((size_t)F0*DIM*2);
    u16* Wt1b = (u16*)alloc((size_t)DIM*DIM*2);
    u16* Wt2a = (u16*)alloc((size_t)DIM*DIM*2);
    u16* Wt2b = (u16*)alloc((size_t)DIM*DIM*2);
    u16* Wt3a = (u16*)alloc((size_t)DIM*DIM*2);
    u16* Wt3b = (u16*)alloc((size_t)DIM*DIM*2);
    u16* Vc   = (u16*)alloc(11*256*2);
    u16* Wfc  = (u16*)alloc((size_t)DIM*NC*2);
    u16* Xc   = P;  // consumed by layer-1 agg before P is first written
    float* statsA = stats;
    float* statsB = stats + 2*DIM;

    // probe + zero gcur/statsA/statsB in one launch
    probe_kernel<<<1, 256, 0, stream>>>((const u32*)x, ei, mode, gcur, stats);

    // CSR build
    bucketA<<<(NE + EPB - 1)/EPB, 256, 0, stream>>>(ei, mode, bArr, gcur);
    bucketB<<<NBUCK, 256, 0, stream>>>(bArr, gcur, rp, ssrc);

    // canonicalize
    cvt_x<<<(NND*F0)/(256*8), 256, 0, stream>>>((const float*)x, Xc, mode);
    merged_cvt<<<128 + 5*256 + 16 + 11, 256, 0, stream>>>(
        w1a,w1b,w2a,w2b,w3a,w3b,wfc, b1a,b1b,g1,be1,b2a,b2b,g2,be2,b3a,b3b,bfc,
        Wt1a,Wt1b,Wt2a,Wt2b,Wt3a,Wt3b,Wfc,Vc, mode);

    dim3 ggrid(MPAD/TBM, DIM/TBN);   // (782, 2)

    // ---- layer 1 ----
    agg2<16><<<NND/4, 256, 0, stream>>>((const u16*)x, Xc, mode, rp, ssrc, Q,
                                        statsA, Vc, Vc, 0, NND);
    gemm128<<<ggrid, 256, 0, stream>>>(Q, Wt1a, Vc+0*256, P, DIM, F0, 1, statsA, 0);
    gemm128<<<ggrid, 256, 0, stream>>>(P, Wt1b, Vc+1*256, Q, DIM, DIM, 1, statsA, 1);

    // ---- layer 2 (agg applies BN1 affine from statsA) ----
    agg2<32><<<NND/4, 256, 0, stream>>>(Q, Q, mode, rp, ssrc, P,
                                        statsA, Vc+2*256, Vc+3*256, 1, NND);
    gemm128<<<ggrid, 256, 0, stream>>>(P, Wt2a, Vc+4*256, Q, DIM, DIM, 1, statsB, 0);
    gemm128<<<ggrid, 256, 0, stream>>>(Q, Wt2b, Vc+5*256, P, DIM, DIM, 1, statsB, 1);

    // ---- layer 3 (agg applies BN2 affine from statsB) ----
    agg2<32><<<NND/4, 256, 0, stream>>>(P, P, mode, rp, ssrc, Q,
                                        statsB, Vc+6*256, Vc+7*256, 1, NND);
    gemm128<<<ggrid, 256, 0, stream>>>(Q, Wt3a, Vc+8*256, P, DIM, DIM, 1, statsA, 0);
    gemm128<<<ggrid, 256, 0, stream>>>(P, Wt3b, Vc+9*256, Q, DIM, DIM, 1, statsA, 0);

    // ---- FC + log_softmax ----
    fc_lsm<<<NND/16, 256, 0, stream>>>(Q, Wfc, Vc+10*256, d_out, mode, NND);
}

// Round 6
// 1110.457 us; speedup vs baseline: 2.0213x; 1.0387x over previous
//
#include <hip/hip_runtime.h>

typedef unsigned int  u32;
typedef unsigned short u16;

#define NND 100000
#define MPAD 100096
#define NE  3200000
#define F0  128
#define DIM 256
#define NC  16

// CSR bucketing
#define BSH   9
#define NBUCK 196
#define CAP   18432
#define EPB   8192

typedef __bf16 bf16x8 __attribute__((ext_vector_type(8)));
typedef float  f32x4  __attribute__((ext_vector_type(4)));

__device__ __forceinline__ float b2f(u16 h){ return __uint_as_float(((u32)h)<<16); }
__device__ __forceinline__ u16 f2b(float f){
    u32 u = __float_as_uint(f);
    return (u16)((u + 0x7fffu + ((u>>16)&1u)) >> 16);
}
__device__ __forceinline__ float lo16(u32 u){ return __uint_as_float(u<<16); }
__device__ __forceinline__ float hi16(u32 u){ return __uint_as_float(u & 0xffff0000u); }

__device__ __forceinline__ void gload16(const u16* g, u16* l){
    __builtin_amdgcn_global_load_lds(
        (const __attribute__((address_space(1))) u32*)g,
        (__attribute__((address_space(3))) u32*)l, 16, 0, 0);
}

// ---------------- probe + zero-init (gcur, statsA, statsB) ----------------
__global__ void probe_kernel(const u32* __restrict__ xw, const int* __restrict__ ei,
                             int* __restrict__ mode, int* __restrict__ gcur,
                             float* __restrict__ stats){
    int t = threadIdx.x;
    if(t < NBUCK) gcur[t] = 0;
    #pragma unroll
    for(int i=0;i<4;i++) stats[t + 256*i] = 0.f;
    if(t==0){
        int insane = 0;
        for(int i=0;i<64;i++){
            u32 w  = xw[i];
            u32 lo = w & 0xffffu;
            u32 e  = (lo >> 7) & 0xff;
            if(lo != 0 && (e < 48 || e > 208)) insane++;
        }
        mode[0] = (insane > 8) ? 1 : 0;
        int zeros = 0;
        for(int i=0;i<16;i++) if(ei[2*i+1]==0) zeros++;
        mode[1] = (zeros==16) ? 1 : 0;
    }
}

__device__ __forceinline__ int ld_src(const int* ei, int i64f, long e){
    return i64f ? ei[2*e] : ei[e];
}
__device__ __forceinline__ int ld_dst(const int* ei, int i64f, long e){
    return i64f ? ei[2*((long)NE + e)] : ei[(long)NE + e];
}

// ---------------- CSR build, Phase A ----------------
__global__ __launch_bounds__(256) void bucketA(const int* __restrict__ ei,
        const int* __restrict__ mode, u32* __restrict__ bucketArr,
        int* __restrict__ gcur){
    __shared__ u32 stag[EPB];
    __shared__ u16 sbuck[EPB];
    __shared__ int cnt[NBUCK];
    __shared__ int ofs[NBUCK];
    __shared__ int wofs[NBUCK];
    __shared__ int gbase[NBUCK];
    __shared__ int ps[256];
    int tid = threadIdx.x;
    int i64f = mode[1];
    long e0 = (long)blockIdx.x * EPB;
    int n = (int)min((long)EPB, (long)NE - e0);
    if(tid < NBUCK) cnt[tid] = 0;
    __syncthreads();
    for(int i=tid;i<n;i+=256){
        int d = ld_dst(ei, i64f, e0+i);
        atomicAdd(&cnt[d>>BSH], 1);
    }
    __syncthreads();
    ps[tid] = (tid < NBUCK) ? cnt[tid] : 0;
    __syncthreads();
    for(int o=1;o<256;o<<=1){
        int v = (tid>=o) ? ps[tid-o] : 0;
        __syncthreads();
        ps[tid] += v;
        __syncthreads();
    }
    if(tid < NBUCK){
        int ex = ps[tid] - cnt[tid];
        ofs[tid] = ex; wofs[tid] = ex;
        gbase[tid] = cnt[tid] ? atomicAdd(&gcur[tid], cnt[tid]) : 0;
    }
    __syncthreads();
    for(int i=tid;i<n;i+=256){
        int s = ld_src(ei, i64f, e0+i);
        int d = ld_dst(ei, i64f, e0+i);
        int b = d>>BSH;
        int r = atomicAdd(&wofs[b], 1);
        stag[r]  = ((u32)s<<BSH) | (u32)(d & ((1<<BSH)-1));
        sbuck[r] = (u16)b;
    }
    __syncthreads();
    for(int i=tid;i<n;i+=256){
        int b = sbuck[i];
        int pos = gbase[b] + (i - ofs[b]);
        if(pos < CAP) bucketArr[(size_t)b*CAP + pos] = stag[i];
    }
}

// ---------------- CSR build, Phase B ----------------
__global__ __launch_bounds__(256) void bucketB(const u32* __restrict__ bucketArr,
        const int* __restrict__ gcnt,
        int* __restrict__ rp, int* __restrict__ ssrc){
    __shared__ u32 stag[CAP];
    __shared__ int deg[512];
    __shared__ int lrp[512];
    __shared__ int cur[512];
    __shared__ int ps[256];
    int b = blockIdx.x, tid = threadIdx.x;
    ps[tid] = (tid < NBUCK) ? gcnt[tid] : 0;
    __syncthreads();
    for(int o=1;o<256;o<<=1){
        int v = (tid>=o) ? ps[tid-o] : 0;
        __syncthreads();
        ps[tid] += v;
        __syncthreads();
    }
    int base = (b>0) ? ps[b-1] : 0;
    int n = min(gcnt[b], CAP);
    const u32* ba = bucketArr + (size_t)b*CAP;
    deg[tid] = 0; deg[tid+256] = 0;
    __syncthreads();
    for(int i=tid;i<n;i+=256){
        atomicAdd(&deg[ba[i] & 511], 1);
    }
    __syncthreads();
    ps[tid] = deg[2*tid] + deg[2*tid+1];
    __syncthreads();
    for(int o=1;o<256;o<<=1){
        int v = (tid>=o) ? ps[tid-o] : 0;
        __syncthreads();
        ps[tid] += v;
        __syncthreads();
    }
    {
        int ep = (tid==0) ? 0 : ps[tid-1];
        lrp[2*tid]   = ep;
        lrp[2*tid+1] = ep + deg[2*tid];
        cur[2*tid]   = lrp[2*tid];
        cur[2*tid+1] = lrp[2*tid+1];
    }
    __syncthreads();
    for(int i=tid;i<512;i+=256){
        int node = (b<<BSH) + i;
        if(node <= NND) rp[node] = base + lrp[i];
    }
    for(int i=tid;i<n;i+=256){
        u32 v = ba[i];
        int r = atomicAdd(&cur[v & 511], 1);
        stag[r] = v >> BSH;
    }
    __syncthreads();
    for(int i=tid;i<n;i+=256){
        ssrc[base + i] = (int)stag[i];
    }
}

// ---------------- x canonicalization (f32 -> bf16) ----------------
__global__ void cvt_x(const float* __restrict__ xf, u16* __restrict__ Xc,
                      const int* __restrict__ mode){
    if(!mode[0]) return;
    size_t i = ((size_t)blockIdx.x*256 + threadIdx.x)*8;
    float4 a = *(const float4*)(xf+i);
    float4 b = *(const float4*)(xf+i+4);
    uint4 pk;
    pk.x = (u32)f2b(a.x) | ((u32)f2b(a.y)<<16);
    pk.y = (u32)f2b(a.z) | ((u32)f2b(a.w)<<16);
    pk.z = (u32)f2b(b.x) | ((u32)f2b(b.y)<<16);
    pk.w = (u32)f2b(b.z) | ((u32)f2b(b.w)<<16);
    *(uint4*)(Xc + i) = pk;
}

// ---------------- merged weight/bias canonicalization ----------------
__device__ __forceinline__ float ldf(const void* p, int i, int f32f){
    return f32f ? ((const float*)p)[i] : b2f(((const u16*)p)[i]);
}
__global__ void merged_cvt(
        const void* w1a, const void* w1b, const void* w2a, const void* w2b,
        const void* w3a, const void* w3b, const void* wfc,
        const void* b1a, const void* b1b, const void* g1, const void* be1,
        const void* b2a, const void* b2b, const void* g2, const void* be2,
        const void* b3a, const void* b3b, const void* bfcp,
        u16* __restrict__ Wt1a, u16* __restrict__ Wt1b, u16* __restrict__ Wt2a,
        u16* __restrict__ Wt2b, u16* __restrict__ Wt3a, u16* __restrict__ Wt3b,
        u16* __restrict__ Wfc, u16* __restrict__ Vc, const int* __restrict__ mode){
    int b = blockIdx.x, t = threadIdx.x;
    int f32f = mode[0];
    if(b < 128){
        int id = b*256 + t;
        int k = id / DIM, n = id % DIM;
        Wt1a[n*F0 + k] = f2b(ldf(w1a, id, f32f));
        return;
    }
    b -= 128;
    if(b < 5*256){
        int wi = b >> 8;
        const void* W = (wi==0)?w1b:(wi==1)?w2a:(wi==2)?w2b:(wi==3)?w3a:w3b;
        u16* Wt = (wi==0)?Wt1b:(wi==1)?Wt2a:(wi==2)?Wt2b:(wi==3)?Wt3a:Wt3b;
        int id = (b & 255)*256 + t;
        int k = id / DIM, n = id % DIM;
        Wt[n*DIM + k] = f2b(ldf(W, id, f32f));
        return;
    }
    b -= 5*256;
    if(b < 16){
        int id = b*256 + t;
        int k = id / NC, c = id % NC;
        Wfc[c*DIM + k] = f2b(ldf(wfc, id, f32f));
        return;
    }
    b -= 16;
    {
        const void* ps[11] = {b1a,b1b,g1,be1,b2a,b2b,g2,be2,b3a,b3b,bfcp};
        int lens[11] = {DIM,DIM,DIM,DIM,DIM,DIM,DIM,DIM,DIM,DIM,NC};
        if(t < lens[b]) Vc[b*256 + t] = f2b(ldf(ps[b], t, f32f));
    }
}

// ---------------- aggregation: 16B lanes, unroll-8 ----------------
template<int LPI>
__global__ __launch_bounds__(256) void agg2(const u16* __restrict__ hA,
        const u16* __restrict__ hB, const int* __restrict__ mode,
        const int* __restrict__ rp, const int* __restrict__ ssrc,
        u16* __restrict__ out,
        const float* __restrict__ stats, const u16* __restrict__ g,
        const u16* __restrict__ be, int use_bn, int M){
    const int F = LPI*8;
    const int IPW = 64/LPI;
    int node = blockIdx.x*4 + (threadIdx.x>>6);
    if(node >= M) return;
    int lane = threadIdx.x & 63;
    int li   = lane & (LPI-1);
    int slot = lane / LPI;
    const u16* h = (LPI==16 && mode[0]) ? hB : hA;
    const int boff = li*8;

    int e0 = rp[node], e1 = rp[node+1];
    int n_items = e1 - e0 + 1;
    float acc[8] = {0.f,0.f,0.f,0.f,0.f,0.f,0.f,0.f};

    auto item = [&](int i)->int { return (i==0) ? node : ssrc[e0 + i - 1]; };
    auto addu = [&](uint4 u){
        acc[0]+=lo16(u.x); acc[1]+=hi16(u.x);
        acc[2]+=lo16(u.y); acc[3]+=hi16(u.y);
        acc[4]+=lo16(u.z); acc[5]+=hi16(u.z);
        acc[6]+=lo16(u.w); acc[7]+=hi16(u.w);
    };

    int i = 0;
    for(; i + 8*IPW <= n_items; i += 8*IPW){
        int s[8];
        #pragma unroll
        for(int j=0;j<8;j++) s[j] = item(i + j*IPW + slot);
        uint4 u[8];
        #pragma unroll
        for(int j=0;j<8;j++) u[j] = *(const uint4*)(h + (size_t)s[j]*F + boff);
        #pragma unroll
        for(int j=0;j<8;j++) addu(u[j]);
    }
    for(; i + IPW <= n_items; i += IPW){
        int s = item(i + slot);
        addu(*(const uint4*)(h + (size_t)s*F + boff));
    }
    if(i < n_items){
        int r = n_items - i;
        if(slot < r){
            int s = item(i + slot);
            addu(*(const uint4*)(h + (size_t)s*F + boff));
        }
    }

    #pragma unroll
    for(int j=0;j<8;j++){
        if(LPI==16) acc[j] += __shfl_xor(acc[j], 16);
        acc[j] += __shfl_xor(acc[j], 32);
    }

    if(slot == 0){
        float res[8];
        if(use_bn){
            float inv_m = 1.0f / (float)M;
            float cnt = (float)n_items;
            #pragma unroll
            for(int j=0;j<8;j++){
                int f = boff + j;
                float mean = stats[f]*inv_m;
                float var  = fmaxf(stats[F+f]*inv_m - mean*mean, 0.f);
                float rstd = rsqrtf(var + 1e-5f);
                float gg = b2f(g[f]);
                float a = gg*rstd;
                float bb = b2f(be[f]) - a*mean;
                res[j] = a*acc[j] + cnt*bb;
            }
        } else {
            #pragma unroll
            for(int j=0;j<8;j++) res[j] = acc[j];
        }
        uint4 o;
        o.x = (u32)f2b(res[0]) | ((u32)f2b(res[1])<<16);
        o.y = (u32)f2b(res[2]) | ((u32)f2b(res[3])<<16);
        o.z = (u32)f2b(res[4]) | ((u32)f2b(res[5])<<16);
        o.w = (u32)f2b(res[6]) | ((u32)f2b(res[7])<<16);
        *(uint4*)(out + (size_t)node*F + boff) = o;
    }
}

// ---------------- fused per-layer MLP: C = relu(relu(A@Wa+ba)@Wb+bb), z in LDS ----
// M-tile 64, N = 256 full width, 256 threads (4 waves, each a 64-col strip).
#define FBM 64
#define FBK 32
#define ZP  264          // z row stride (elements): +8 pad -> 2-way LDS conflicts only
__global__ __launch_bounds__(256) void mlp_fused(
        const u16* __restrict__ A, const u16* __restrict__ WaT,
        const u16* __restrict__ ba, const u16* __restrict__ WbT,
        const u16* __restrict__ bb, u16* __restrict__ C,
        int Ka, float* __restrict__ stats, int do_stats){
    __shared__ __align__(16) u16 lA[FBM*FBK];     // 4 KB
    __shared__ __align__(16) u16 lB[DIM*FBK];     // 16 KB
    __shared__ __align__(16) u16 zt[FBM*ZP];      // 33 KB
    __shared__ float colS[DIM], colS2[DIM];
    int tid = threadIdx.x;
    int w = tid>>6, lane = tid&63;
    int q = lane>>4, mr = lane&15;
    int m0 = blockIdx.x*FBM;

    if(do_stats){ colS[tid]=0.f; colS2[tid]=0.f; }

    f32x4 acc[4][4];   // [row-tile][col-tile]
    #pragma unroll
    for(int i=0;i<4;i++)
        #pragma unroll
        for(int c=0;c<4;c++) acc[i][c] = (f32x4){0.f,0.f,0.f,0.f};

    // ---- phase 1: z = relu(A @ Wa + ba) ----
    {
        const u16* gA = A + (size_t)(m0 + (tid>>2))*Ka + (tid&3)*8;
        u16* lAd = &lA[tid*16/2];   // contiguous: lane-order * 16B
        for(int k0=0; k0<Ka; k0+=FBK){
            gload16(gA, lAd); gA += FBK;
            #pragma unroll
            for(int j=0;j<4;j++){
                int s = j*256 + tid;
                gload16(WaT + (size_t)(s>>2)*Ka + k0 + (s&3)*8, &lB[s*8]);
            }
            __syncthreads();
            bf16x8 af[4], bf[4];
            #pragma unroll
            for(int i=0;i<4;i++)
                af[i] = *reinterpret_cast<const bf16x8*>(&lA[(i*16+mr)*FBK + q*8]);
            #pragma unroll
            for(int c=0;c<4;c++)
                bf[c] = *reinterpret_cast<const bf16x8*>(&lB[(w*64+c*16+mr)*FBK + q*8]);
            #pragma unroll
            for(int i=0;i<4;i++)
                #pragma unroll
                for(int c=0;c<4;c++)
                    acc[i][c] = __builtin_amdgcn_mfma_f32_16x16x32_bf16(af[i], bf[c], acc[i][c], 0, 0, 0);
            __syncthreads();
        }
    }
    // z -> LDS (bf16), reset acc
    #pragma unroll
    for(int c=0;c<4;c++){
        int col = w*64 + c*16 + mr;
        float bav = b2f(ba[col]);
        #pragma unroll
        for(int i=0;i<4;i++){
            #pragma unroll
            for(int r=0;r<4;r++){
                int row = i*16 + q*4 + r;
                zt[row*ZP + col] = f2b(fmaxf(acc[i][c][r] + bav, 0.f));
            }
            acc[i][c] = (f32x4){0.f,0.f,0.f,0.f};
        }
    }
    __syncthreads();

    // ---- phase 2: C = relu(z @ Wb + bb) ----
    for(int k0=0; k0<DIM; k0+=FBK){
        #pragma unroll
        for(int j=0;j<4;j++){
            int s = j*256 + tid;
            gload16(WbT + (size_t)(s>>2)*DIM + k0 + (s&3)*8, &lB[s*8]);
        }
        __syncthreads();
        bf16x8 af[4], bf[4];
        #pragma unroll
        for(int i=0;i<4;i++)
            af[i] = *reinterpret_cast<const bf16x8*>(&zt[(i*16+mr)*ZP + k0 + q*8]);
        #pragma unroll
        for(int c=0;c<4;c++)
            bf[c] = *reinterpret_cast<const bf16x8*>(&lB[(w*64+c*16+mr)*FBK + q*8]);
        #pragma unroll
        for(int i=0;i<4;i++)
            #pragma unroll
            for(int c=0;c<4;c++)
                acc[i][c] = __builtin_amdgcn_mfma_f32_16x16x32_bf16(af[i], bf[c], acc[i][c], 0, 0, 0);
        __syncthreads();
    }

    // ---- epilogue: bias + relu + store + stats ----
    #pragma unroll
    for(int c=0;c<4;c++){
        int col = w*64 + c*16 + mr;
        float bv = b2f(bb[col]);
        float s = 0.f, s2 = 0.f;
        #pragma unroll
        for(int i=0;i<4;i++){
            int row = m0 + i*16 + q*4;
            #pragma unroll
            for(int r=0;r<4;r++){
                float v = fmaxf(acc[i][c][r] + bv, 0.f);
                u16 o = f2b(v);
                C[(size_t)(row + r)*DIM + col] = o;
                if(do_stats && (row + r) < NND){
                    float vr = b2f(o);
                    s += vr; s2 += vr*vr;
                }
            }
        }
        if(do_stats){
            atomicAdd(&colS[col], s);
            atomicAdd(&colS2[col], s2);
        }
    }
    if(do_stats){
        __syncthreads();
        atomicAdd(&stats[tid], colS[tid]);
        atomicAdd(&stats[DIM+tid], colS2[tid]);
    }
}

// ---------------- FC (256->16) + log_softmax ----------------
__global__ __launch_bounds__(256) void fc_lsm(const u16* __restrict__ h,
        const u16* __restrict__ wfcT, const u16* __restrict__ bfc,
        void* __restrict__ out, const int* __restrict__ mode, int M){
    __shared__ float lds[256];
    __shared__ float rmx[16], rls[16];
    int tid = threadIdx.x;
    int r = tid>>4, c = tid&15;
    int row = blockIdx.x*16 + r;
    float acc = b2f(bfc[c]);
    const u16* hp = h + (size_t)row*DIM;
    const u16* wp = wfcT + c*DIM;
    for(int k=0;k<DIM;k+=8){
        uint4 hv = *(const uint4*)(hp+k);
        uint4 wv = *(const uint4*)(wp+k);
        acc += lo16(hv.x)*lo16(wv.x) + hi16(hv.x)*hi16(wv.x)
             + lo16(hv.y)*lo16(wv.y) + hi16(hv.y)*hi16(wv.y)
             + lo16(hv.z)*lo16(wv.z) + hi16(hv.z)*hi16(wv.z)
             + lo16(hv.w)*lo16(wv.w) + hi16(hv.w)*hi16(wv.w);
    }
    lds[tid] = acc;
    __syncthreads();
    if(c==0){
        float mx = -1e30f;
        for(int i=0;i<NC;i++) mx = fmaxf(mx, lds[r*NC+i]);
        float s = 0.f;
        for(int i=0;i<NC;i++) s += expf(lds[r*NC+i] - mx);
        rmx[r] = mx; rls[r] = logf(s);
    }
    __syncthreads();
    if(row < M){
        float v = acc - rmx[r] - rls[r];
        if(mode[0]) ((float*)out)[(size_t)row*NC + c] = v;
        else        ((u16*)out)[(size_t)row*NC + c] = f2b(v);
    }
}

extern "C" void kernel_launch(void* const* d_in, const int* in_sizes, int n_in,
                              void* d_out, int out_size, void* d_ws, size_t ws_size,
                              hipStream_t stream){
    const void* x   = d_in[0];
    const int*  ei  = (const int*)d_in[1];
    const void* w1a = d_in[2];  const void* b1a = d_in[3];
    const void* w1b = d_in[4];  const void* b1b = d_in[5];
    const void* g1  = d_in[6];  const void* be1 = d_in[7];
    const void* w2a = d_in[8];  const void* b2a = d_in[9];
    const void* w2b = d_in[10]; const void* b2b = d_in[11];
    const void* g2  = d_in[12]; const void* be2 = d_in[13];
    const void* w3a = d_in[14]; const void* b3a = d_in[15];
    const void* w3b = d_in[16]; const void* b3b = d_in[17];
    const void* wfc = d_in[18]; const void* bfc = d_in[19];

    char* base = (char*)d_ws;
    size_t off = 0;
    auto alloc = [&](size_t bytes)->void*{
        void* p = base + off;
        off = (off + bytes + 255) & ~(size_t)255;
        return p;
    };
    u16*  P     = (u16*)alloc((size_t)MPAD*DIM*2);   // aliases Xc
    u16*  Q     = (u16*)alloc((size_t)MPAD*DIM*2);
    int*  ssrc  = (int*)alloc((size_t)NE*4);
    u32*  bArr  = (u32*)alloc((size_t)NBUCK*CAP*4);
    int*  gcur  = (int*)alloc((size_t)NBUCK*4);
    int*  rp    = (int*)alloc((size_t)(NND+1)*4);
    float* stats= (float*)alloc(4*DIM*4);            // statsA | statsB
    int*  mode  = (int*)alloc(16);
    u16* Wt1a = (u16*)alloc((size_t)F0*DIM*2);
    u16* Wt1b = (u16*)alloc((size_t)DIM*DIM*2);
    u16* Wt2a = (u16*)alloc((size_t)DIM*DIM*2);
    u16* Wt2b = (u16*)alloc((size_t)DIM*DIM*2);
    u16* Wt3a = (u16*)alloc((size_t)DIM*DIM*2);
    u16* Wt3b = (u16*)alloc((size_t)DIM*DIM*2);
    u16* Vc   = (u16*)alloc(11*256*2);
    u16* Wfc  = (u16*)alloc((size_t)DIM*NC*2);
    u16* Xc   = P;
    float* statsA = stats;
    float* statsB = stats + 2*DIM;

    probe_kernel<<<1, 256, 0, stream>>>((const u32*)x, ei, mode, gcur, stats);

    bucketA<<<(NE + EPB - 1)/EPB, 256, 0, stream>>>(ei, mode, bArr, gcur);
    bucketB<<<NBUCK, 256, 0, stream>>>(bArr, gcur, rp, ssrc);

    cvt_x<<<(NND*F0)/(256*8), 256, 0, stream>>>((const float*)x, Xc, mode);
    merged_cvt<<<128 + 5*256 + 16 + 11, 256, 0, stream>>>(
        w1a,w1b,w2a,w2b,w3a,w3b,wfc, b1a,b1b,g1,be1,b2a,b2b,g2,be2,b3a,b3b,bfc,
        Wt1a,Wt1b,Wt2a,Wt2b,Wt3a,Wt3b,Wfc,Vc, mode);

    int mgrid = MPAD/FBM;   // 1564

    // ---- layer 1 ----
    agg2<16><<<NND/4, 256, 0, stream>>>((const u16*)x, Xc, mode, rp, ssrc, Q,
                                        statsA, Vc, Vc, 0, NND);
    mlp_fused<<<mgrid, 256, 0, stream>>>(Q, Wt1a, Vc+0*256, Wt1b, Vc+1*256, P,
                                         F0, statsA, 1);

    // ---- layer 2 (agg applies BN1 affine from statsA) ----
    agg2<32><<<NND/4, 256, 0, stream>>>(P, P, mode, rp, ssrc, Q,
                                        statsA, Vc+2*256, Vc+3*256, 1, NND);
    mlp_fused<<<mgrid, 256, 0, stream>>>(Q, Wt2a, Vc+4*256, Wt2b, Vc+5*256, P,
                                         DIM, statsB, 1);

    // ---- layer 3 (agg applies BN2 affine from statsB) ----
    agg2<32><<<NND/4, 256, 0, stream>>>(P, P, mode, rp, ssrc, Q,
                                        statsB, Vc+6*256, Vc+7*256, 1, NND);
    mlp_fused<<<mgrid, 256, 0, stream>>>(Q, Wt3a, Vc+8*256, Wt3b, Vc+9*256, P,
                                         DIM, statsA, 0);

    // ---- FC + log_softmax ----
    fc_lsm<<<NND/16, 256, 0, stream>>>(P, Wfc, Vc+10*256, d_out, mode, NND);
}

// Round 7
// 1090.377 us; speedup vs baseline: 2.0585x; 1.0184x over previous
//
#include <hip/hip_runtime.h>

typedef unsigned int  u32;
typedef unsigned short u16;

#define NND 100000
#define MPAD 100096
#define NE  3200000
#define F0  128
#define DIM 256
#define NC  16

// CSR bucketing
#define BSH   9
#define NBUCK 196
#define CAP   18432
#define EPB   8192

typedef __bf16 bf16x8 __attribute__((ext_vector_type(8)));
typedef float  f32x4  __attribute__((ext_vector_type(4)));

__device__ __forceinline__ float b2f(u16 h){ return __uint_as_float(((u32)h)<<16); }
__device__ __forceinline__ u16 f2b(float f){
    u32 u = __float_as_uint(f);
    return (u16)((u + 0x7fffu + ((u>>16)&1u)) >> 16);
}
__device__ __forceinline__ float lo16(u32 u){ return __uint_as_float(u<<16); }
__device__ __forceinline__ float hi16(u32 u){ return __uint_as_float(u & 0xffff0000u); }

// ---------------- probe + zero-init (gcur, statsA, statsB) ----------------
__global__ void probe_kernel(const u32* __restrict__ xw, const int* __restrict__ ei,
                             int* __restrict__ mode, int* __restrict__ gcur,
                             float* __restrict__ stats){
    int t = threadIdx.x;
    if(t < NBUCK) gcur[t] = 0;
    #pragma unroll
    for(int i=0;i<4;i++) stats[t + 256*i] = 0.f;
    if(t==0){
        int insane = 0;
        for(int i=0;i<64;i++){
            u32 w  = xw[i];
            u32 lo = w & 0xffffu;
            u32 e  = (lo >> 7) & 0xff;
            if(lo != 0 && (e < 48 || e > 208)) insane++;
        }
        mode[0] = (insane > 8) ? 1 : 0;
        int zeros = 0;
        for(int i=0;i<16;i++) if(ei[2*i+1]==0) zeros++;
        mode[1] = (zeros==16) ? 1 : 0;
    }
}

__device__ __forceinline__ int ld_src(const int* ei, int i64f, long e){
    return i64f ? ei[2*e] : ei[e];
}
__device__ __forceinline__ int ld_dst(const int* ei, int i64f, long e){
    return i64f ? ei[2*((long)NE + e)] : ei[(long)NE + e];
}

// ---------------- CSR build, Phase A ----------------
__global__ __launch_bounds__(256) void bucketA(const int* __restrict__ ei,
        const int* __restrict__ mode, u32* __restrict__ bucketArr,
        int* __restrict__ gcur){
    __shared__ u32 stag[EPB];
    __shared__ u16 sbuck[EPB];
    __shared__ int cnt[NBUCK];
    __shared__ int ofs[NBUCK];
    __shared__ int wofs[NBUCK];
    __shared__ int gbase[NBUCK];
    __shared__ int ps[256];
    int tid = threadIdx.x;
    int i64f = mode[1];
    long e0 = (long)blockIdx.x * EPB;
    int n = (int)min((long)EPB, (long)NE - e0);
    if(tid < NBUCK) cnt[tid] = 0;
    __syncthreads();
    for(int i=tid;i<n;i+=256){
        int d = ld_dst(ei, i64f, e0+i);
        atomicAdd(&cnt[d>>BSH], 1);
    }
    __syncthreads();
    ps[tid] = (tid < NBUCK) ? cnt[tid] : 0;
    __syncthreads();
    for(int o=1;o<256;o<<=1){
        int v = (tid>=o) ? ps[tid-o] : 0;
        __syncthreads();
        ps[tid] += v;
        __syncthreads();
    }
    if(tid < NBUCK){
        int ex = ps[tid] - cnt[tid];
        ofs[tid] = ex; wofs[tid] = ex;
        gbase[tid] = cnt[tid] ? atomicAdd(&gcur[tid], cnt[tid]) : 0;
    }
    __syncthreads();
    for(int i=tid;i<n;i+=256){
        int s = ld_src(ei, i64f, e0+i);
        int d = ld_dst(ei, i64f, e0+i);
        int b = d>>BSH;
        int r = atomicAdd(&wofs[b], 1);
        stag[r]  = ((u32)s<<BSH) | (u32)(d & ((1<<BSH)-1));
        sbuck[r] = (u16)b;
    }
    __syncthreads();
    for(int i=tid;i<n;i+=256){
        int b = sbuck[i];
        int pos = gbase[b] + (i - ofs[b]);
        if(pos < CAP) bucketArr[(size_t)b*CAP + pos] = stag[i];
    }
}

// ---------------- CSR build, Phase B ----------------
__global__ __launch_bounds__(256) void bucketB(const u32* __restrict__ bucketArr,
        const int* __restrict__ gcnt,
        int* __restrict__ rp, int* __restrict__ ssrc){
    __shared__ u32 stag[CAP];
    __shared__ int deg[512];
    __shared__ int lrp[512];
    __shared__ int cur[512];
    __shared__ int ps[256];
    int b = blockIdx.x, tid = threadIdx.x;
    ps[tid] = (tid < NBUCK) ? gcnt[tid] : 0;
    __syncthreads();
    for(int o=1;o<256;o<<=1){
        int v = (tid>=o) ? ps[tid-o] : 0;
        __syncthreads();
        ps[tid] += v;
        __syncthreads();
    }
    int base = (b>0) ? ps[b-1] : 0;
    int n = min(gcnt[b], CAP);
    const u32* ba = bucketArr + (size_t)b*CAP;
    deg[tid] = 0; deg[tid+256] = 0;
    __syncthreads();
    for(int i=tid;i<n;i+=256){
        atomicAdd(&deg[ba[i] & 511], 1);
    }
    __syncthreads();
    ps[tid] = deg[2*tid] + deg[2*tid+1];
    __syncthreads();
    for(int o=1;o<256;o<<=1){
        int v = (tid>=o) ? ps[tid-o] : 0;
        __syncthreads();
        ps[tid] += v;
        __syncthreads();
    }
    {
        int ep = (tid==0) ? 0 : ps[tid-1];
        lrp[2*tid]   = ep;
        lrp[2*tid+1] = ep + deg[2*tid];
        cur[2*tid]   = lrp[2*tid];
        cur[2*tid+1] = lrp[2*tid+1];
    }
    __syncthreads();
    for(int i=tid;i<512;i+=256){
        int node = (b<<BSH) + i;
        if(node <= NND) rp[node] = base + lrp[i];
    }
    for(int i=tid;i<n;i+=256){
        u32 v = ba[i];
        int r = atomicAdd(&cur[v & 511], 1);
        stag[r] = v >> BSH;
    }
    __syncthreads();
    for(int i=tid;i<n;i+=256){
        ssrc[base + i] = (int)stag[i];
    }
}

// ---------------- x canonicalization (f32 -> bf16) ----------------
__global__ void cvt_x(const float* __restrict__ xf, u16* __restrict__ Xc,
                      const int* __restrict__ mode){
    if(!mode[0]) return;
    size_t i = ((size_t)blockIdx.x*256 + threadIdx.x)*8;
    float4 a = *(const float4*)(xf+i);
    float4 b = *(const float4*)(xf+i+4);
    uint4 pk;
    pk.x = (u32)f2b(a.x) | ((u32)f2b(a.y)<<16);
    pk.y = (u32)f2b(a.z) | ((u32)f2b(a.w)<<16);
    pk.z = (u32)f2b(b.x) | ((u32)f2b(b.y)<<16);
    pk.w = (u32)f2b(b.z) | ((u32)f2b(b.w)<<16);
    *(uint4*)(Xc + i) = pk;
}

// ---------------- merged weight/bias canonicalization ----------------
__device__ __forceinline__ float ldf(const void* p, int i, int f32f){
    return f32f ? ((const float*)p)[i] : b2f(((const u16*)p)[i]);
}
__global__ void merged_cvt(
        const void* w1a, const void* w1b, const void* w2a, const void* w2b,
        const void* w3a, const void* w3b, const void* wfc,
        const void* b1a, const void* b1b, const void* g1, const void* be1,
        const void* b2a, const void* b2b, const void* g2, const void* be2,
        const void* b3a, const void* b3b, const void* bfcp,
        u16* __restrict__ Wt1a, u16* __restrict__ Wt1b, u16* __restrict__ Wt2a,
        u16* __restrict__ Wt2b, u16* __restrict__ Wt3a, u16* __restrict__ Wt3b,
        u16* __restrict__ Wfc, u16* __restrict__ Vc, const int* __restrict__ mode){
    int b = blockIdx.x, t = threadIdx.x;
    int f32f = mode[0];
    if(b < 128){
        int id = b*256 + t;
        int k = id / DIM, n = id % DIM;
        Wt1a[n*F0 + k] = f2b(ldf(w1a, id, f32f));
        return;
    }
    b -= 128;
    if(b < 5*256){
        int wi = b >> 8;
        const void* W = (wi==0)?w1b:(wi==1)?w2a:(wi==2)?w2b:(wi==3)?w3a:w3b;
        u16* Wt = (wi==0)?Wt1b:(wi==1)?Wt2a:(wi==2)?Wt2b:(wi==3)?Wt3a:Wt3b;
        int id = (b & 255)*256 + t;
        int k = id / DIM, n = id % DIM;
        Wt[n*DIM + k] = f2b(ldf(W, id, f32f));
        return;
    }
    b -= 5*256;
    if(b < 16){
        int id = b*256 + t;
        int k = id / NC, c = id % NC;
        Wfc[c*DIM + k] = f2b(ldf(wfc, id, f32f));
        return;
    }
    b -= 16;
    {
        const void* ps[11] = {b1a,b1b,g1,be1,b2a,b2b,g2,be2,b3a,b3b,bfcp};
        int lens[11] = {DIM,DIM,DIM,DIM,DIM,DIM,DIM,DIM,DIM,DIM,NC};
        if(t < lens[b]) Vc[b*256 + t] = f2b(ldf(ps[b], t, f32f));
    }
}

// ---------------- aggregation: 16B lanes, unroll-8 ----------------
template<int LPI>
__global__ __launch_bounds__(256) void agg2(const u16* __restrict__ hA,
        const u16* __restrict__ hB, const int* __restrict__ mode,
        const int* __restrict__ rp, const int* __restrict__ ssrc,
        u16* __restrict__ out,
        const float* __restrict__ stats, const u16* __restrict__ g,
        const u16* __restrict__ be, int use_bn, int M){
    const int F = LPI*8;
    const int IPW = 64/LPI;
    int node = blockIdx.x*4 + (threadIdx.x>>6);
    if(node >= M) return;
    int lane = threadIdx.x & 63;
    int li   = lane & (LPI-1);
    int slot = lane / LPI;
    const u16* h = (LPI==16 && mode[0]) ? hB : hA;
    const int boff = li*8;

    int e0 = rp[node], e1 = rp[node+1];
    int n_items = e1 - e0 + 1;
    float acc[8] = {0.f,0.f,0.f,0.f,0.f,0.f,0.f,0.f};

    auto item = [&](int i)->int { return (i==0) ? node : ssrc[e0 + i - 1]; };
    auto addu = [&](uint4 u){
        acc[0]+=lo16(u.x); acc[1]+=hi16(u.x);
        acc[2]+=lo16(u.y); acc[3]+=hi16(u.y);
        acc[4]+=lo16(u.z); acc[5]+=hi16(u.z);
        acc[6]+=lo16(u.w); acc[7]+=hi16(u.w);
    };

    int i = 0;
    for(; i + 8*IPW <= n_items; i += 8*IPW){
        int s[8];
        #pragma unroll
        for(int j=0;j<8;j++) s[j] = item(i + j*IPW + slot);
        uint4 u[8];
        #pragma unroll
        for(int j=0;j<8;j++) u[j] = *(const uint4*)(h + (size_t)s[j]*F + boff);
        #pragma unroll
        for(int j=0;j<8;j++) addu(u[j]);
    }
    for(; i + IPW <= n_items; i += IPW){
        int s = item(i + slot);
        addu(*(const uint4*)(h + (size_t)s*F + boff));
    }
    if(i < n_items){
        int r = n_items - i;
        if(slot < r){
            int s = item(i + slot);
            addu(*(const uint4*)(h + (size_t)s*F + boff));
        }
    }

    #pragma unroll
    for(int j=0;j<8;j++){
        if(LPI==16) acc[j] += __shfl_xor(acc[j], 16);
        acc[j] += __shfl_xor(acc[j], 32);
    }

    if(slot == 0){
        float res[8];
        if(use_bn){
            float inv_m = 1.0f / (float)M;
            float cnt = (float)n_items;
            #pragma unroll
            for(int j=0;j<8;j++){
                int f = boff + j;
                float mean = stats[f]*inv_m;
                float var  = fmaxf(stats[F+f]*inv_m - mean*mean, 0.f);
                float rstd = rsqrtf(var + 1e-5f);
                float gg = b2f(g[f]);
                float a = gg*rstd;
                float bb = b2f(be[f]) - a*mean;
                res[j] = a*acc[j] + cnt*bb;
            }
        } else {
            #pragma unroll
            for(int j=0;j<8;j++) res[j] = acc[j];
        }
        uint4 o;
        o.x = (u32)f2b(res[0]) | ((u32)f2b(res[1])<<16);
        o.y = (u32)f2b(res[2]) | ((u32)f2b(res[3])<<16);
        o.z = (u32)f2b(res[4]) | ((u32)f2b(res[5])<<16);
        o.w = (u32)f2b(res[6]) | ((u32)f2b(res[7])<<16);
        *(uint4*)(out + (size_t)node*F + boff) = o;
    }
}

// ---------------- fused per-layer MLP, direct-register operand loads -------------
// C = relu(relu(A@Wa+ba)@Wb+bb). z kept in LDS. Only 2-3 barriers per block.
// Optional fused BN-stats; optional fused FC(256->16)+log_softmax (layer 3).
#define FBM 64
#define ZP  264          // z row stride: 528 B -> 16B-aligned, 2-way LDS conflicts (free)
__global__ __launch_bounds__(256) void mlp_fused(
        const u16* __restrict__ A, const u16* __restrict__ WaT,
        const u16* __restrict__ ba, const u16* __restrict__ WbT,
        const u16* __restrict__ bb, u16* __restrict__ C,
        int Ka, float* __restrict__ stats, int do_stats,
        int do_fc, const u16* __restrict__ WfcT, const u16* __restrict__ bfc,
        void* __restrict__ out, const int* __restrict__ mode){
    __shared__ __align__(16) u16 zt[FBM*ZP];      // 33 KB
    __shared__ float colS[DIM], colS2[DIM];
    int tid = threadIdx.x;
    int w = tid>>6, lane = tid&63;
    int q = lane>>4, mr = lane&15;
    int m0 = blockIdx.x*FBM;

    if(do_stats){ colS[tid]=0.f; colS2[tid]=0.f; }

    f32x4 acc[4][4];   // [row-tile i][col-tile c]; cols w*64+c*16+mr, rows i*16+q*4+r
    #pragma unroll
    for(int i=0;i<4;i++)
        #pragma unroll
        for(int c=0;c<4;c++) acc[i][c] = (f32x4){0.f,0.f,0.f,0.f};

    // ---- phase 1: acc = A @ Wa  (all operands direct from global/L2) ----
    for(int k0=0; k0<Ka; k0+=32){
        bf16x8 af[4], bf[4];
        #pragma unroll
        for(int i=0;i<4;i++)
            af[i] = *reinterpret_cast<const bf16x8*>(A + (size_t)(m0 + i*16 + mr)*Ka + k0 + q*8);
        #pragma unroll
        for(int c=0;c<4;c++)
            bf[c] = *reinterpret_cast<const bf16x8*>(WaT + (size_t)(w*64 + c*16 + mr)*Ka + k0 + q*8);
        #pragma unroll
        for(int i=0;i<4;i++)
            #pragma unroll
            for(int c=0;c<4;c++)
                acc[i][c] = __builtin_amdgcn_mfma_f32_16x16x32_bf16(af[i], bf[c], acc[i][c], 0, 0, 0);
    }
    // z = relu(acc + ba) -> LDS, reset acc
    #pragma unroll
    for(int c=0;c<4;c++){
        int col = w*64 + c*16 + mr;
        float bav = b2f(ba[col]);
        #pragma unroll
        for(int i=0;i<4;i++){
            #pragma unroll
            for(int r=0;r<4;r++){
                int row = i*16 + q*4 + r;
                zt[row*ZP + col] = f2b(fmaxf(acc[i][c][r] + bav, 0.f));
            }
            acc[i][c] = (f32x4){0.f,0.f,0.f,0.f};
        }
    }
    __syncthreads();

    // ---- phase 2: acc = z @ Wb  (z from LDS, Wb direct) ----
    for(int k0=0; k0<DIM; k0+=32){
        bf16x8 af[4], bf[4];
        #pragma unroll
        for(int i=0;i<4;i++)
            af[i] = *reinterpret_cast<const bf16x8*>(&zt[(i*16+mr)*ZP + k0 + q*8]);
        #pragma unroll
        for(int c=0;c<4;c++)
            bf[c] = *reinterpret_cast<const bf16x8*>(WbT + (size_t)(w*64 + c*16 + mr)*DIM + k0 + q*8);
        #pragma unroll
        for(int i=0;i<4;i++)
            #pragma unroll
            for(int c=0;c<4;c++)
                acc[i][c] = __builtin_amdgcn_mfma_f32_16x16x32_bf16(af[i], bf[c], acc[i][c], 0, 0, 0);
    }

    if(!do_fc){
        // ---- epilogue: bias + relu + store + stats ----
        #pragma unroll
        for(int c=0;c<4;c++){
            int col = w*64 + c*16 + mr;
            float bv = b2f(bb[col]);
            float s = 0.f, s2 = 0.f;
            #pragma unroll
            for(int i=0;i<4;i++){
                int row = m0 + i*16 + q*4;
                #pragma unroll
                for(int r=0;r<4;r++){
                    float v = fmaxf(acc[i][c][r] + bv, 0.f);
                    u16 o = f2b(v);
                    C[(size_t)(row + r)*DIM + col] = o;
                    if(do_stats && (row + r) < NND){
                        float vr = b2f(o);
                        s += vr; s2 += vr*vr;
                    }
                }
            }
            if(do_stats){
                atomicAdd(&colS[col], s);
                atomicAdd(&colS2[col], s2);
            }
        }
        if(do_stats){
            __syncthreads();
            atomicAdd(&stats[tid], colS[tid]);
            atomicAdd(&stats[DIM+tid], colS2[tid]);
        }
    } else {
        // ---- layer-3 epilogue: h3 -> LDS, FC via MFMA, log-softmax, store out ----
        __syncthreads();   // all zt reads of phase 2 complete
        #pragma unroll
        for(int c=0;c<4;c++){
            int col = w*64 + c*16 + mr;
            float bv = b2f(bb[col]);
            #pragma unroll
            for(int i=0;i<4;i++)
                #pragma unroll
                for(int r=0;r<4;r++)
                    zt[(i*16 + q*4 + r)*ZP + col] = f2b(fmaxf(acc[i][c][r] + bv, 0.f));
        }
        __syncthreads();
        // wave w handles rows w*16 .. w*16+15
        f32x4 fa = (f32x4){0.f,0.f,0.f,0.f};
        for(int k0=0; k0<DIM; k0+=32){
            bf16x8 za = *reinterpret_cast<const bf16x8*>(&zt[(w*16+mr)*ZP + k0 + q*8]);
            bf16x8 wb = *reinterpret_cast<const bf16x8*>(WfcT + (size_t)mr*DIM + k0 + q*8);
            fa = __builtin_amdgcn_mfma_f32_16x16x32_bf16(za, wb, fa, 0, 0, 0);
        }
        float bv = b2f(bfc[mr]);
        int f32o = mode[0];
        #pragma unroll
        for(int r=0;r<4;r++){
            float val = fa[r] + bv;
            float m = val;
            #pragma unroll
            for(int o=1;o<16;o<<=1) m = fmaxf(m, __shfl_xor(m, o));
            float ex = expf(val - m);
            float s = ex;
            #pragma unroll
            for(int o=1;o<16;o<<=1) s += __shfl_xor(s, o);
            float res = val - m - logf(s);
            int row = m0 + w*16 + q*4 + r;
            if(row < NND){
                if(f32o) ((float*)out)[(size_t)row*NC + mr] = res;
                else     ((u16*)out)[(size_t)row*NC + mr] = f2b(res);
            }
        }
    }
}

extern "C" void kernel_launch(void* const* d_in, const int* in_sizes, int n_in,
                              void* d_out, int out_size, void* d_ws, size_t ws_size,
                              hipStream_t stream){
    const void* x   = d_in[0];
    const int*  ei  = (const int*)d_in[1];
    const void* w1a = d_in[2];  const void* b1a = d_in[3];
    const void* w1b = d_in[4];  const void* b1b = d_in[5];
    const void* g1  = d_in[6];  const void* be1 = d_in[7];
    const void* w2a = d_in[8];  const void* b2a = d_in[9];
    const void* w2b = d_in[10]; const void* b2b = d_in[11];
    const void* g2  = d_in[12]; const void* be2 = d_in[13];
    const void* w3a = d_in[14]; const void* b3a = d_in[15];
    const void* w3b = d_in[16]; const void* b3b = d_in[17];
    const void* wfc = d_in[18]; const void* bfc = d_in[19];

    char* base = (char*)d_ws;
    size_t off = 0;
    auto alloc = [&](size_t bytes)->void*{
        void* p = base + off;
        off = (off + bytes + 255) & ~(size_t)255;
        return p;
    };
    u16*  P     = (u16*)alloc((size_t)MPAD*DIM*2);   // aliases Xc
    u16*  Q     = (u16*)alloc((size_t)MPAD*DIM*2);
    int*  ssrc  = (int*)alloc((size_t)NE*4);
    u32*  bArr  = (u32*)alloc((size_t)NBUCK*CAP*4);
    int*  gcur  = (int*)alloc((size_t)NBUCK*4);
    int*  rp    = (int*)alloc((size_t)(NND+1)*4);
    float* stats= (float*)alloc(4*DIM*4);            // statsA | statsB
    int*  mode  = (int*)alloc(16);
    u16* Wt1a = (u16*)alloc((size_t)F0*DIM*2);
    u16* Wt1b = (u16*)alloc((size_t)DIM*DIM*2);
    u16* Wt2a = (u16*)alloc((size_t)DIM*DIM*2);
    u16* Wt2b = (u16*)alloc((size_t)DIM*DIM*2);
    u16* Wt3a = (u16*)alloc((size_t)DIM*DIM*2);
    u16* Wt3b = (u16*)alloc((size_t)DIM*DIM*2);
    u16* Vc   = (u16*)alloc(11*256*2);
    u16* Wfc  = (u16*)alloc((size_t)DIM*NC*2);
    u16* Xc   = P;
    float* statsA = stats;
    float* statsB = stats + 2*DIM;

    probe_kernel<<<1, 256, 0, stream>>>((const u32*)x, ei, mode, gcur, stats);

    bucketA<<<(NE + EPB - 1)/EPB, 256, 0, stream>>>(ei, mode, bArr, gcur);
    bucketB<<<NBUCK, 256, 0, stream>>>(bArr, gcur, rp, ssrc);

    cvt_x<<<(NND*F0)/(256*8), 256, 0, stream>>>((const float*)x, Xc, mode);
    merged_cvt<<<128 + 5*256 + 16 + 11, 256, 0, stream>>>(
        w1a,w1b,w2a,w2b,w3a,w3b,wfc, b1a,b1b,g1,be1,b2a,b2b,g2,be2,b3a,b3b,bfc,
        Wt1a,Wt1b,Wt2a,Wt2b,Wt3a,Wt3b,Wfc,Vc, mode);

    int mgrid = MPAD/FBM;   // 1564

    // ---- layer 1 ----
    agg2<16><<<NND/4, 256, 0, stream>>>((const u16*)x, Xc, mode, rp, ssrc, Q,
                                        statsA, Vc, Vc, 0, NND);
    mlp_fused<<<mgrid, 256, 0, stream>>>(Q, Wt1a, Vc+0*256, Wt1b, Vc+1*256, P,
                                         F0, statsA, 1, 0, Wfc, Vc+10*256, d_out, mode);

    // ---- layer 2 (agg applies BN1 affine from statsA) ----
    agg2<32><<<NND/4, 256, 0, stream>>>(P, P, mode, rp, ssrc, Q,
                                        statsA, Vc+2*256, Vc+3*256, 1, NND);
    mlp_fused<<<mgrid, 256, 0, stream>>>(Q, Wt2a, Vc+4*256, Wt2b, Vc+5*256, P,
                                         DIM, statsB, 1, 0, Wfc, Vc+10*256, d_out, mode);

    // ---- layer 3 (agg applies BN2 affine from statsB; FC+lsm fused in epilogue) ----
    agg2<32><<<NND/4, 256, 0, stream>>>(P, P, mode, rp, ssrc, Q,
                                        statsB, Vc+6*256, Vc+7*256, 1, NND);
    mlp_fused<<<mgrid, 256, 0, stream>>>(Q, Wt3a, Vc+8*256, Wt3b, Vc+9*256, P,
                                         DIM, statsA, 0, 1, Wfc, Vc+10*256, d_out, mode);
}

// Round 8
// 1055.206 us; speedup vs baseline: 2.1271x; 1.0333x over previous
//
#include <hip/hip_runtime.h>

typedef unsigned int  u32;
typedef unsigned short u16;

#define NND 100000
#define MPAD 100096
#define NE  3200000
#define F0  128
#define DIM 256
#define NC  16

// CSR bucketing
#define BSH   9
#define NBUCK 196
#define CAP   18432
#define EPB   8192

typedef __bf16 bf16x8 __attribute__((ext_vector_type(8)));
typedef float  f32x4  __attribute__((ext_vector_type(4)));

__device__ __forceinline__ float b2f(u16 h){ return __uint_as_float(((u32)h)<<16); }
__device__ __forceinline__ u16 f2b(float f){
    u32 u = __float_as_uint(f);
    return (u16)((u + 0x7fffu + ((u>>16)&1u)) >> 16);
}
__device__ __forceinline__ float lo16(u32 u){ return __uint_as_float(u<<16); }
__device__ __forceinline__ float hi16(u32 u){ return __uint_as_float(u & 0xffff0000u); }

// ---------------- probe + zero-init (gcur, statsA, statsB) ----------------
__global__ void probe_kernel(const u32* __restrict__ xw, const int* __restrict__ ei,
                             int* __restrict__ mode, int* __restrict__ gcur,
                             float* __restrict__ stats){
    int t = threadIdx.x;
    if(t < NBUCK) gcur[t] = 0;
    #pragma unroll
    for(int i=0;i<4;i++) stats[t + 256*i] = 0.f;
    if(t==0){
        int insane = 0;
        for(int i=0;i<64;i++){
            u32 w  = xw[i];
            u32 lo = w & 0xffffu;
            u32 e  = (lo >> 7) & 0xff;
            if(lo != 0 && (e < 48 || e > 208)) insane++;
        }
        mode[0] = (insane > 8) ? 1 : 0;
        int zeros = 0;
        for(int i=0;i<16;i++) if(ei[2*i+1]==0) zeros++;
        mode[1] = (zeros==16) ? 1 : 0;
    }
}

__device__ __forceinline__ int ld_src(const int* ei, int i64f, long e){
    return i64f ? ei[2*e] : ei[e];
}
__device__ __forceinline__ int ld_dst(const int* ei, int i64f, long e){
    return i64f ? ei[2*((long)NE + e)] : ei[(long)NE + e];
}

// ---------------- CSR build, Phase A ----------------
__global__ __launch_bounds__(256) void bucketA(const int* __restrict__ ei,
        const int* __restrict__ mode, u32* __restrict__ bucketArr,
        int* __restrict__ gcur){
    __shared__ u32 stag[EPB];
    __shared__ u16 sbuck[EPB];
    __shared__ int cnt[NBUCK];
    __shared__ int ofs[NBUCK];
    __shared__ int wofs[NBUCK];
    __shared__ int gbase[NBUCK];
    __shared__ int ps[256];
    int tid = threadIdx.x;
    int i64f = mode[1];
    long e0 = (long)blockIdx.x * EPB;
    int n = (int)min((long)EPB, (long)NE - e0);
    if(tid < NBUCK) cnt[tid] = 0;
    __syncthreads();
    for(int i=tid;i<n;i+=256){
        int d = ld_dst(ei, i64f, e0+i);
        atomicAdd(&cnt[d>>BSH], 1);
    }
    __syncthreads();
    ps[tid] = (tid < NBUCK) ? cnt[tid] : 0;
    __syncthreads();
    for(int o=1;o<256;o<<=1){
        int v = (tid>=o) ? ps[tid-o] : 0;
        __syncthreads();
        ps[tid] += v;
        __syncthreads();
    }
    if(tid < NBUCK){
        int ex = ps[tid] - cnt[tid];
        ofs[tid] = ex; wofs[tid] = ex;
        gbase[tid] = cnt[tid] ? atomicAdd(&gcur[tid], cnt[tid]) : 0;
    }
    __syncthreads();
    for(int i=tid;i<n;i+=256){
        int s = ld_src(ei, i64f, e0+i);
        int d = ld_dst(ei, i64f, e0+i);
        int b = d>>BSH;
        int r = atomicAdd(&wofs[b], 1);
        stag[r]  = ((u32)s<<BSH) | (u32)(d & ((1<<BSH)-1));
        sbuck[r] = (u16)b;
    }
    __syncthreads();
    for(int i=tid;i<n;i+=256){
        int b = sbuck[i];
        int pos = gbase[b] + (i - ofs[b]);
        if(pos < CAP) bucketArr[(size_t)b*CAP + pos] = stag[i];
    }
}

// ---------------- CSR build, Phase B ----------------
__global__ __launch_bounds__(256) void bucketB(const u32* __restrict__ bucketArr,
        const int* __restrict__ gcnt,
        int* __restrict__ rp, int* __restrict__ ssrc){
    __shared__ u32 stag[CAP];
    __shared__ int deg[512];
    __shared__ int lrp[512];
    __shared__ int cur[512];
    __shared__ int ps[256];
    int b = blockIdx.x, tid = threadIdx.x;
    ps[tid] = (tid < NBUCK) ? gcnt[tid] : 0;
    __syncthreads();
    for(int o=1;o<256;o<<=1){
        int v = (tid>=o) ? ps[tid-o] : 0;
        __syncthreads();
        ps[tid] += v;
        __syncthreads();
    }
    int base = (b>0) ? ps[b-1] : 0;
    int n = min(gcnt[b], CAP);
    const u32* ba = bucketArr + (size_t)b*CAP;
    deg[tid] = 0; deg[tid+256] = 0;
    __syncthreads();
    for(int i=tid;i<n;i+=256){
        atomicAdd(&deg[ba[i] & 511], 1);
    }
    __syncthreads();
    ps[tid] = deg[2*tid] + deg[2*tid+1];
    __syncthreads();
    for(int o=1;o<256;o<<=1){
        int v = (tid>=o) ? ps[tid-o] : 0;
        __syncthreads();
        ps[tid] += v;
        __syncthreads();
    }
    {
        int ep = (tid==0) ? 0 : ps[tid-1];
        lrp[2*tid]   = ep;
        lrp[2*tid+1] = ep + deg[2*tid];
        cur[2*tid]   = lrp[2*tid];
        cur[2*tid+1] = lrp[2*tid+1];
    }
    __syncthreads();
    for(int i=tid;i<512;i+=256){
        int node = (b<<BSH) + i;
        if(node <= NND) rp[node] = base + lrp[i];
    }
    for(int i=tid;i<n;i+=256){
        u32 v = ba[i];
        int r = atomicAdd(&cur[v & 511], 1);
        stag[r] = v >> BSH;
    }
    __syncthreads();
    for(int i=tid;i<n;i+=256){
        ssrc[base + i] = (int)stag[i];
    }
}

// ---------------- x canonicalization (f32 -> bf16) ----------------
__global__ void cvt_x(const float* __restrict__ xf, u16* __restrict__ Xc,
                      const int* __restrict__ mode){
    if(!mode[0]) return;
    size_t i = ((size_t)blockIdx.x*256 + threadIdx.x)*8;
    float4 a = *(const float4*)(xf+i);
    float4 b = *(const float4*)(xf+i+4);
    uint4 pk;
    pk.x = (u32)f2b(a.x) | ((u32)f2b(a.y)<<16);
    pk.y = (u32)f2b(a.z) | ((u32)f2b(a.w)<<16);
    pk.z = (u32)f2b(b.x) | ((u32)f2b(b.y)<<16);
    pk.w = (u32)f2b(b.z) | ((u32)f2b(b.w)<<16);
    *(uint4*)(Xc + i) = pk;
}

// ---------------- merged weight/bias canonicalization ----------------
__device__ __forceinline__ float ldf(const void* p, int i, int f32f){
    return f32f ? ((const float*)p)[i] : b2f(((const u16*)p)[i]);
}
__global__ void merged_cvt(
        const void* w1a, const void* w1b, const void* w2a, const void* w2b,
        const void* w3a, const void* w3b, const void* wfc,
        const void* b1a, const void* b1b, const void* g1, const void* be1,
        const void* b2a, const void* b2b, const void* g2, const void* be2,
        const void* b3a, const void* b3b, const void* bfcp,
        u16* __restrict__ Wt1a, u16* __restrict__ Wt1b, u16* __restrict__ Wt2a,
        u16* __restrict__ Wt2b, u16* __restrict__ Wt3a, u16* __restrict__ Wt3b,
        u16* __restrict__ Wfc, u16* __restrict__ Vc, const int* __restrict__ mode){
    int b = blockIdx.x, t = threadIdx.x;
    int f32f = mode[0];
    if(b < 128){
        int id = b*256 + t;
        int k = id / DIM, n = id % DIM;
        Wt1a[n*F0 + k] = f2b(ldf(w1a, id, f32f));
        return;
    }
    b -= 128;
    if(b < 5*256){
        int wi = b >> 8;
        const void* W = (wi==0)?w1b:(wi==1)?w2a:(wi==2)?w2b:(wi==3)?w3a:w3b;
        u16* Wt = (wi==0)?Wt1b:(wi==1)?Wt2a:(wi==2)?Wt2b:(wi==3)?Wt3a:Wt3b;
        int id = (b & 255)*256 + t;
        int k = id / DIM, n = id % DIM;
        Wt[n*DIM + k] = f2b(ldf(W, id, f32f));
        return;
    }
    b -= 5*256;
    if(b < 16){
        int id = b*256 + t;
        int k = id / NC, c = id % NC;
        Wfc[c*DIM + k] = f2b(ldf(wfc, id, f32f));
        return;
    }
    b -= 16;
    {
        const void* ps[11] = {b1a,b1b,g1,be1,b2a,b2b,g2,be2,b3a,b3b,bfcp};
        int lens[11] = {DIM,DIM,DIM,DIM,DIM,DIM,DIM,DIM,DIM,DIM,NC};
        if(t < lens[b]) Vc[b*256 + t] = f2b(ldf(ps[b], t, f32f));
    }
}

// ---------------- aggregation: 16B lanes, unroll-8 ----------------
template<int LPI>
__global__ __launch_bounds__(256) void agg2(const u16* __restrict__ hA,
        const u16* __restrict__ hB, const int* __restrict__ mode,
        const int* __restrict__ rp, const int* __restrict__ ssrc,
        u16* __restrict__ out,
        const float* __restrict__ stats, const u16* __restrict__ g,
        const u16* __restrict__ be, int use_bn, int M){
    const int F = LPI*8;
    const int IPW = 64/LPI;
    int node = blockIdx.x*4 + (threadIdx.x>>6);
    if(node >= M) return;
    int lane = threadIdx.x & 63;
    int li   = lane & (LPI-1);
    int slot = lane / LPI;
    const u16* h = (LPI==16 && mode[0]) ? hB : hA;
    const int boff = li*8;

    int e0 = rp[node], e1 = rp[node+1];
    int n_items = e1 - e0 + 1;
    float acc[8] = {0.f,0.f,0.f,0.f,0.f,0.f,0.f,0.f};

    auto item = [&](int i)->int { return (i==0) ? node : ssrc[e0 + i - 1]; };
    auto addu = [&](uint4 u){
        acc[0]+=lo16(u.x); acc[1]+=hi16(u.x);
        acc[2]+=lo16(u.y); acc[3]+=hi16(u.y);
        acc[4]+=lo16(u.z); acc[5]+=hi16(u.z);
        acc[6]+=lo16(u.w); acc[7]+=hi16(u.w);
    };

    int i = 0;
    for(; i + 8*IPW <= n_items; i += 8*IPW){
        int s[8];
        #pragma unroll
        for(int j=0;j<8;j++) s[j] = item(i + j*IPW + slot);
        uint4 u[8];
        #pragma unroll
        for(int j=0;j<8;j++) u[j] = *(const uint4*)(h + (size_t)s[j]*F + boff);
        #pragma unroll
        for(int j=0;j<8;j++) addu(u[j]);
    }
    for(; i + IPW <= n_items; i += IPW){
        int s = item(i + slot);
        addu(*(const uint4*)(h + (size_t)s*F + boff));
    }
    if(i < n_items){
        int r = n_items - i;
        if(slot < r){
            int s = item(i + slot);
            addu(*(const uint4*)(h + (size_t)s*F + boff));
        }
    }

    #pragma unroll
    for(int j=0;j<8;j++){
        if(LPI==16) acc[j] += __shfl_xor(acc[j], 16);
        acc[j] += __shfl_xor(acc[j], 32);
    }

    if(slot == 0){
        float res[8];
        if(use_bn){
            float inv_m = 1.0f / (float)M;
            float cnt = (float)n_items;
            #pragma unroll
            for(int j=0;j<8;j++){
                int f = boff + j;
                float mean = stats[f]*inv_m;
                float var  = fmaxf(stats[F+f]*inv_m - mean*mean, 0.f);
                float rstd = rsqrtf(var + 1e-5f);
                float gg = b2f(g[f]);
                float a = gg*rstd;
                float bb = b2f(be[f]) - a*mean;
                res[j] = a*acc[j] + cnt*bb;
            }
        } else {
            #pragma unroll
            for(int j=0;j<8;j++) res[j] = acc[j];
        }
        uint4 o;
        o.x = (u32)f2b(res[0]) | ((u32)f2b(res[1])<<16);
        o.y = (u32)f2b(res[2]) | ((u32)f2b(res[3])<<16);
        o.z = (u32)f2b(res[4]) | ((u32)f2b(res[5])<<16);
        o.w = (u32)f2b(res[6]) | ((u32)f2b(res[7])<<16);
        *(uint4*)(out + (size_t)node*F + boff) = o;
    }
}

// ---------------- fused per-layer MLP, K templated + register-prefetch pipeline ----
// C = relu(relu(A@Wa+ba)@Wb+bb). z kept in LDS. 2-3 barriers per block total.
#define FBM 64
#define ZP  264
template<int KA>
__global__ __launch_bounds__(256) void mlp_fused(
        const u16* __restrict__ A, const u16* __restrict__ WaT,
        const u16* __restrict__ ba, const u16* __restrict__ WbT,
        const u16* __restrict__ bb, u16* __restrict__ C,
        float* __restrict__ stats, int do_stats,
        int do_fc, const u16* __restrict__ WfcT, const u16* __restrict__ bfc,
        void* __restrict__ out, const int* __restrict__ mode){
    __shared__ __align__(16) u16 zt[FBM*ZP];      // 33 KB
    __shared__ float colS[DIM], colS2[DIM];
    int tid = threadIdx.x;
    int w = tid>>6, lane = tid&63;
    int q = lane>>4, mr = lane&15;
    int m0 = blockIdx.x*FBM;

    if(do_stats){ colS[tid]=0.f; colS2[tid]=0.f; }

    f32x4 acc[4][4];
    #pragma unroll
    for(int i=0;i<4;i++)
        #pragma unroll
        for(int c=0;c<4;c++) acc[i][c] = (f32x4){0.f,0.f,0.f,0.f};

    // ---- phase 1: acc = A @ Wa  (register double-buffer pipeline) ----
    {
        const int NK = KA/32;
        bf16x8 a0[4], b0[4];
        #pragma unroll
        for(int i=0;i<4;i++)
            a0[i] = *reinterpret_cast<const bf16x8*>(A + (size_t)(m0 + i*16 + mr)*KA + q*8);
        #pragma unroll
        for(int c=0;c<4;c++)
            b0[c] = *reinterpret_cast<const bf16x8*>(WaT + (size_t)(w*64 + c*16 + mr)*KA + q*8);
        #pragma unroll
        for(int k=0;k<NK;k++){
            bf16x8 a1[4], b1[4];
            if(k+1<NK){
                #pragma unroll
                for(int i=0;i<4;i++)
                    a1[i] = *reinterpret_cast<const bf16x8*>(A + (size_t)(m0 + i*16 + mr)*KA + (k+1)*32 + q*8);
                #pragma unroll
                for(int c=0;c<4;c++)
                    b1[c] = *reinterpret_cast<const bf16x8*>(WaT + (size_t)(w*64 + c*16 + mr)*KA + (k+1)*32 + q*8);
            }
            #pragma unroll
            for(int i=0;i<4;i++)
                #pragma unroll
                for(int c=0;c<4;c++)
                    acc[i][c] = __builtin_amdgcn_mfma_f32_16x16x32_bf16(a0[i], b0[c], acc[i][c], 0, 0, 0);
            if(k+1<NK){
                #pragma unroll
                for(int i=0;i<4;i++){ a0[i]=a1[i]; b0[i]=b1[i]; }
            }
        }
    }
    // z = relu(acc + ba) -> LDS, reset acc
    #pragma unroll
    for(int c=0;c<4;c++){
        int col = w*64 + c*16 + mr;
        float bav = b2f(ba[col]);
        #pragma unroll
        for(int i=0;i<4;i++){
            #pragma unroll
            for(int r=0;r<4;r++){
                int row = i*16 + q*4 + r;
                zt[row*ZP + col] = f2b(fmaxf(acc[i][c][r] + bav, 0.f));
            }
            acc[i][c] = (f32x4){0.f,0.f,0.f,0.f};
        }
    }
    __syncthreads();

    // ---- phase 2: acc = z @ Wb  (z from LDS, Wb prefetched) ----
    {
        const int NK = DIM/32;
        bf16x8 b0[4];
        #pragma unroll
        for(int c=0;c<4;c++)
            b0[c] = *reinterpret_cast<const bf16x8*>(WbT + (size_t)(w*64 + c*16 + mr)*DIM + q*8);
        #pragma unroll
        for(int k=0;k<NK;k++){
            bf16x8 b1[4];
            if(k+1<NK){
                #pragma unroll
                for(int c=0;c<4;c++)
                    b1[c] = *reinterpret_cast<const bf16x8*>(WbT + (size_t)(w*64 + c*16 + mr)*DIM + (k+1)*32 + q*8);
            }
            bf16x8 af[4];
            #pragma unroll
            for(int i=0;i<4;i++)
                af[i] = *reinterpret_cast<const bf16x8*>(&zt[(i*16+mr)*ZP + k*32 + q*8]);
            #pragma unroll
            for(int i=0;i<4;i++)
                #pragma unroll
                for(int c=0;c<4;c++)
                    acc[i][c] = __builtin_amdgcn_mfma_f32_16x16x32_bf16(af[i], b0[c], acc[i][c], 0, 0, 0);
            if(k+1<NK){
                #pragma unroll
                for(int c=0;c<4;c++) b0[c]=b1[c];
            }
        }
    }

    if(!do_fc){
        #pragma unroll
        for(int c=0;c<4;c++){
            int col = w*64 + c*16 + mr;
            float bv = b2f(bb[col]);
            float s = 0.f, s2 = 0.f;
            #pragma unroll
            for(int i=0;i<4;i++){
                int row = m0 + i*16 + q*4;
                #pragma unroll
                for(int r=0;r<4;r++){
                    float v = fmaxf(acc[i][c][r] + bv, 0.f);
                    u16 o = f2b(v);
                    C[(size_t)(row + r)*DIM + col] = o;
                    if(do_stats && (row + r) < NND){
                        float vr = b2f(o);
                        s += vr; s2 += vr*vr;
                    }
                }
            }
            if(do_stats){
                atomicAdd(&colS[col], s);
                atomicAdd(&colS2[col], s2);
            }
        }
        if(do_stats){
            __syncthreads();
            atomicAdd(&stats[tid], colS[tid]);
            atomicAdd(&stats[DIM+tid], colS2[tid]);
        }
    } else {
        __syncthreads();
        #pragma unroll
        for(int c=0;c<4;c++){
            int col = w*64 + c*16 + mr;
            float bv = b2f(bb[col]);
            #pragma unroll
            for(int i=0;i<4;i++)
                #pragma unroll
                for(int r=0;r<4;r++)
                    zt[(i*16 + q*4 + r)*ZP + col] = f2b(fmaxf(acc[i][c][r] + bv, 0.f));
        }
        __syncthreads();
        f32x4 fa = (f32x4){0.f,0.f,0.f,0.f};
        #pragma unroll
        for(int k0=0; k0<DIM; k0+=32){
            bf16x8 za = *reinterpret_cast<const bf16x8*>(&zt[(w*16+mr)*ZP + k0 + q*8]);
            bf16x8 wb = *reinterpret_cast<const bf16x8*>(WfcT + (size_t)mr*DIM + k0 + q*8);
            fa = __builtin_amdgcn_mfma_f32_16x16x32_bf16(za, wb, fa, 0, 0, 0);
        }
        float bv = b2f(bfc[mr]);
        int f32o = mode[0];
        #pragma unroll
        for(int r=0;r<4;r++){
            float val = fa[r] + bv;
            float m = val;
            #pragma unroll
            for(int o=1;o<16;o<<=1) m = fmaxf(m, __shfl_xor(m, o));
            float ex = expf(val - m);
            float s = ex;
            #pragma unroll
            for(int o=1;o<16;o<<=1) s += __shfl_xor(s, o);
            float res = val - m - logf(s);
            int row = m0 + w*16 + q*4 + r;
            if(row < NND){
                if(f32o) ((float*)out)[(size_t)row*NC + mr] = res;
                else     ((u16*)out)[(size_t)row*NC + mr] = f2b(res);
            }
        }
    }
}

extern "C" void kernel_launch(void* const* d_in, const int* in_sizes, int n_in,
                              void* d_out, int out_size, void* d_ws, size_t ws_size,
                              hipStream_t stream){
    const void* x   = d_in[0];
    const int*  ei  = (const int*)d_in[1];
    const void* w1a = d_in[2];  const void* b1a = d_in[3];
    const void* w1b = d_in[4];  const void* b1b = d_in[5];
    const void* g1  = d_in[6];  const void* be1 = d_in[7];
    const void* w2a = d_in[8];  const void* b2a = d_in[9];
    const void* w2b = d_in[10]; const void* b2b = d_in[11];
    const void* g2  = d_in[12]; const void* be2 = d_in[13];
    const void* w3a = d_in[14]; const void* b3a = d_in[15];
    const void* w3b = d_in[16]; const void* b3b = d_in[17];
    const void* wfc = d_in[18]; const void* bfc = d_in[19];

    char* base = (char*)d_ws;
    size_t off = 0;
    auto alloc = [&](size_t bytes)->void*{
        void* p = base + off;
        off = (off + bytes + 255) & ~(size_t)255;
        return p;
    };
    u16*  P     = (u16*)alloc((size_t)MPAD*DIM*2);   // aliases Xc
    u16*  Q     = (u16*)alloc((size_t)MPAD*DIM*2);
    int*  ssrc  = (int*)alloc((size_t)NE*4);
    u32*  bArr  = (u32*)alloc((size_t)NBUCK*CAP*4);
    int*  gcur  = (int*)alloc((size_t)NBUCK*4);
    int*  rp    = (int*)alloc((size_t)(NND+1)*4);
    float* stats= (float*)alloc(4*DIM*4);            // statsA | statsB
    int*  mode  = (int*)alloc(16);
    u16* Wt1a = (u16*)alloc((size_t)F0*DIM*2);
    u16* Wt1b = (u16*)alloc((size_t)DIM*DIM*2);
    u16* Wt2a = (u16*)alloc((size_t)DIM*DIM*2);
    u16* Wt2b = (u16*)alloc((size_t)DIM*DIM*2);
    u16* Wt3a = (u16*)alloc((size_t)DIM*DIM*2);
    u16* Wt3b = (u16*)alloc((size_t)DIM*DIM*2);
    u16* Vc   = (u16*)alloc(11*256*2);
    u16* Wfc  = (u16*)alloc((size_t)DIM*NC*2);
    u16* Xc   = P;
    float* statsA = stats;
    float* statsB = stats + 2*DIM;

    probe_kernel<<<1, 256, 0, stream>>>((const u32*)x, ei, mode, gcur, stats);

    bucketA<<<(NE + EPB - 1)/EPB, 256, 0, stream>>>(ei, mode, bArr, gcur);
    bucketB<<<NBUCK, 256, 0, stream>>>(bArr, gcur, rp, ssrc);

    cvt_x<<<(NND*F0)/(256*8), 256, 0, stream>>>((const float*)x, Xc, mode);
    merged_cvt<<<128 + 5*256 + 16 + 11, 256, 0, stream>>>(
        w1a,w1b,w2a,w2b,w3a,w3b,wfc, b1a,b1b,g1,be1,b2a,b2b,g2,be2,b3a,b3b,bfc,
        Wt1a,Wt1b,Wt2a,Wt2b,Wt3a,Wt3b,Wfc,Vc, mode);

    int mgrid = MPAD/FBM;   // 1564

    // ---- layer 1 ----
    agg2<16><<<NND/4, 256, 0, stream>>>((const u16*)x, Xc, mode, rp, ssrc, Q,
                                        statsA, Vc, Vc, 0, NND);
    mlp_fused<F0><<<mgrid, 256, 0, stream>>>(Q, Wt1a, Vc+0*256, Wt1b, Vc+1*256, P,
                                             statsA, 1, 0, Wfc, Vc+10*256, d_out, mode);

    // ---- layer 2 (agg applies BN1 affine from statsA) ----
    agg2<32><<<NND/4, 256, 0, stream>>>(P, P, mode, rp, ssrc, Q,
                                        statsA, Vc+2*256, Vc+3*256, 1, NND);
    mlp_fused<DIM><<<mgrid, 256, 0, stream>>>(Q, Wt2a, Vc+4*256, Wt2b, Vc+5*256, P,
                                              statsB, 1, 0, Wfc, Vc+10*256, d_out, mode);

    // ---- layer 3 (agg applies BN2 affine from statsB; FC+lsm fused in epilogue) ----
    agg2<32><<<NND/4, 256, 0, stream>>>(P, P, mode, rp, ssrc, Q,
                                        statsB, Vc+6*256, Vc+7*256, 1, NND);
    mlp_fused<DIM><<<mgrid, 256, 0, stream>>>(Q, Wt3a, Vc+8*256, Wt3b, Vc+9*256, P,
                                              statsA, 0, 1, Wfc, Vc+10*256, d_out, mode);
}